// Round 2
// baseline (1874.721 us; speedup 1.0000x reference)
//
#include <hip/hip_runtime.h>
#include <hip/hip_bf16.h>

// Problem constants
constexpr int BB = 2;        // batch
constexpr int CC = 128;      // channels
constexpr int LL = 4096;     // H*W sequence length
constexpr int DI = 256;      // d_inner
constexpr int DS = 16;       // d_state
constexpr int DR = 8;        // dt_rank
constexpr int DX = 40;       // dt_rank + 2*d_state
constexpr int NZ = 2 * BB;   // branches * batch (flattened "zi" index: br*BB + b)

// ---------------- LayerNorm over C, keep (zi, C, L) layout ----------------
// grid: (LL/64, NZ), block 256.  Input pan/ms are (B, C, L) fp32.
__global__ __launch_bounds__(256) void layernorm_kernel(
    const float* __restrict__ pan, const float* __restrict__ ms,
    const float* __restrict__ wpan, const float* __restrict__ bpan,
    const float* __restrict__ wms, const float* __restrict__ bms,
    float* __restrict__ x3)
{
    const int zi = blockIdx.y;
    const int br = zi >> 1, b = zi & 1;
    const float* inp = br ? ms : pan;
    const float* wp = br ? wms : wpan;
    const float* bp = br ? bms : bpan;
    const int l0 = blockIdx.x * 64;
    const int t = threadIdx.x;
    const int lo = t & 63, c4 = t >> 6;   // c4 in 0..3, each owns 32 channels
    const float* base = inp + (size_t)b * CC * LL + l0 + lo;
    float vals[32];
    float s = 0.f, s2 = 0.f;
    #pragma unroll
    for (int i = 0; i < 32; i++) {
        const int c = c4 * 32 + i;
        const float v = base[(size_t)c * LL];
        vals[i] = v; s += v; s2 += v * v;
    }
    __shared__ float red[2][4][64];
    red[0][c4][lo] = s; red[1][c4][lo] = s2;
    __syncthreads();
    const float S  = red[0][0][lo] + red[0][1][lo] + red[0][2][lo] + red[0][3][lo];
    const float S2 = red[1][0][lo] + red[1][1][lo] + red[1][2][lo] + red[1][3][lo];
    const float mu = S * (1.f / CC);
    const float var = S2 * (1.f / CC) - mu * mu;
    const float rstd = rsqrtf(var + 1e-5f);
    float* out = x3 + (size_t)zi * CC * LL + l0 + lo;
    #pragma unroll
    for (int i = 0; i < 32; i++) {
        const int c = c4 * 32 + i;
        out[(size_t)c * LL] = (vals[i] - mu) * rstd * wp[c] + bp[c];
    }
}

// ---------------- Generic GEMM: out[zi,m,n] = sum_k W[m,k] * X[zi,k,n] --------
// W is fp32 (M,K) row-major, picked per-branch (zi>=BB -> W1). X fp32 (NZ,K,N).
// grid: (N/64, ceil(M/64), NZ), block 256, 64x64 tile, 4x4 per thread.
__global__ __launch_bounds__(256) void gemm_kernel(
    const float* __restrict__ W0, const float* __restrict__ W1,
    const float* __restrict__ X, float* __restrict__ outp,
    const int M, const int K, const int N)
{
    const int zi = blockIdx.z;
    const float* Wm = (zi >= BB) ? W1 : W0;
    const float* Xb = X + (size_t)zi * K * N;
    const int m0 = blockIdx.y * 64, n0 = blockIdx.x * 64;
    const int t = threadIdx.x;
    const int tx = t & 15, ty = t >> 4;
    __shared__ float Ws[16][65];
    __shared__ float Xs[16][64];
    float acc[4][4] = {};
    for (int k0 = 0; k0 < K; k0 += 16) {
        #pragma unroll
        for (int i = 0; i < 4; i++) {
            const int m = (t >> 4) + 16 * i;
            const int gm = m0 + m;
            float v = 0.f;
            if (gm < M) v = Wm[(size_t)gm * K + k0 + (t & 15)];
            Ws[t & 15][m] = v;
        }
        #pragma unroll
        for (int i = 0; i < 4; i++) {
            const int k = (t >> 6) + 4 * i;
            Xs[k][t & 63] = Xb[(size_t)(k0 + k) * N + n0 + (t & 63)];
        }
        __syncthreads();
        #pragma unroll
        for (int kk = 0; kk < 16; kk++) {
            float a[4], bv[4];
            #pragma unroll
            for (int i = 0; i < 4; i++) a[i] = Ws[kk][ty * 4 + i];
            #pragma unroll
            for (int j = 0; j < 4; j++) bv[j] = Xs[kk][tx * 4 + j];
            #pragma unroll
            for (int i = 0; i < 4; i++)
                #pragma unroll
                for (int j = 0; j < 4; j++)
                    acc[i][j] = fmaf(a[i], bv[j], acc[i][j]);
        }
        __syncthreads();
    }
    #pragma unroll
    for (int i = 0; i < 4; i++) {
        const int gm = m0 + ty * 4 + i;
        if (gm >= M) break;
        const size_t base = (size_t)zi * M * N + (size_t)gm * N + n0 + tx * 4;
        #pragma unroll
        for (int j = 0; j < 4; j++) outp[base + j] = acc[i][j];
    }
}

// ---------------- Causal depthwise conv (k=4) + SiLU ----------------
// one thread per 4 consecutive l.  total threads = NZ*DI*LL/4
__global__ __launch_bounds__(256) void conv_silu_kernel(
    const float* __restrict__ xpre,
    const float* __restrict__ cw0, const float* __restrict__ cb0,
    const float* __restrict__ cw1, const float* __restrict__ cb1,
    float* __restrict__ xc)
{
    const int gid = blockIdx.x * 256 + threadIdx.x;
    const int l4 = gid & (LL / 4 - 1);
    const int e = (gid >> 10) & (DI - 1);
    const int zi = gid >> 18;
    const float* cw = (zi >= BB) ? cw1 : cw0;
    const float* cb = (zi >= BB) ? cb1 : cb0;
    const float w0 = cw[e * 4 + 0], w1 = cw[e * 4 + 1];
    const float w2 = cw[e * 4 + 2], w3 = cw[e * 4 + 3];
    const float bias = cb[e];
    const float* xp = xpre + ((size_t)zi * DI + e) * LL;
    float* op = xc + ((size_t)zi * DI + e) * LL;
    const int l0 = l4 * 4;
    float xm3, xm2, xm1;
    if (l0 == 0) { xm3 = 0.f; xm2 = 0.f; xm1 = 0.f; }
    else { xm3 = xp[l0 - 3]; xm2 = xp[l0 - 2]; xm1 = xp[l0 - 1]; }
    const float4 xv = *(const float4*)(xp + l0);
    float o0 = w0 * xm3 + w1 * xm2 + w2 * xm1 + w3 * xv.x + bias;
    float o1 = w0 * xm2 + w1 * xm1 + w2 * xv.x + w3 * xv.y + bias;
    float o2 = w0 * xm1 + w1 * xv.x + w2 * xv.y + w3 * xv.z + bias;
    float o3 = w0 * xv.x + w1 * xv.y + w2 * xv.z + w3 * xv.w + bias;
    float4 r;
    r.x = o0 / (1.f + __expf(-o0));
    r.y = o1 / (1.f + __expf(-o1));
    r.z = o2 / (1.f + __expf(-o2));
    r.w = o3 / (1.f + __expf(-o3));
    *(float4*)(op + l0) = r;
}

__device__ __forceinline__ float softplusf(float x) {
    return (x > 20.f) ? x : log1pf(__expf(x));
}

// ---------------- delta = softplus(W_dt @ dt_low + b_dt) ----------------
// one thread per (zi, e, 4 l's)
__global__ __launch_bounds__(256) void delta_kernel(
    const float* __restrict__ xdbl,
    const float* __restrict__ Wdt0, const float* __restrict__ bdt0,
    const float* __restrict__ Wdt1, const float* __restrict__ bdt1,
    float* __restrict__ delta)
{
    const int gid = blockIdx.x * 256 + threadIdx.x;
    const int l4 = gid & (LL / 4 - 1);
    const int e = (gid >> 10) & (DI - 1);
    const int zi = gid >> 18;
    const float* Wdt = (zi >= BB) ? Wdt1 : Wdt0;
    const float* bdt = (zi >= BB) ? bdt1 : bdt0;
    const float bias = bdt[e];
    const float* xb = xdbl + (size_t)zi * DX * LL;
    const int l0 = l4 * 4;
    float a0 = bias, a1 = bias, a2 = bias, a3 = bias;
    #pragma unroll
    for (int r = 0; r < DR; r++) {
        const float w = Wdt[e * DR + r];
        const float4 v = *(const float4*)(xb + (size_t)r * LL + l0);
        a0 = fmaf(w, v.x, a0); a1 = fmaf(w, v.y, a1);
        a2 = fmaf(w, v.z, a2); a3 = fmaf(w, v.w, a3);
    }
    float4 r4;
    r4.x = softplusf(a0); r4.y = softplusf(a1);
    r4.z = softplusf(a2); r4.w = softplusf(a3);
    *(float4*)(delta + ((size_t)zi * DI + e) * LL + l0) = r4;
}

// ---------------- selective scan + skip + gate ----------------
// 16 lanes (n = state index) per (zi, d).  zy holds z on entry; y written in place.
// grid: NZ*DI*DS/64 = 256 blocks of 64 threads.
__global__ __launch_bounds__(64) void scan_kernel(
    const float* __restrict__ delta, const float* __restrict__ xc,
    const float* __restrict__ xdbl,
    const float* __restrict__ A_log,
    const float* __restrict__ D0, const float* __restrict__ D1,
    float* zy)
{
    const int g = blockIdx.x * 64 + threadIdx.x;
    const int n = g & 15;
    const int grp = g >> 4;          // 0..1023
    const int d = grp & (DI - 1);
    const int zi = grp >> 8;
    const float* dl_p = delta + ((size_t)zi * DI + d) * LL;
    const float* x_p  = xc    + ((size_t)zi * DI + d) * LL;
    float* zy_p       = zy    + ((size_t)zi * DI + d) * LL;
    const float* B_p  = xdbl + (size_t)zi * DX * LL + (size_t)(DR + n) * LL;
    const float* C_p  = xdbl + (size_t)zi * DX * LL + (size_t)(DR + DS + n) * LL;
    const float A_n = -__expf(A_log[d * DS + n]);
    const float Dd = ((zi >= BB) ? D1 : D0)[d];
    float h = 0.f;
    #pragma unroll 4
    for (int l = 0; l < LL; l++) {
        const float dl = dl_p[l];
        const float xv = x_p[l];
        const float a = __expf(dl * A_n);
        const float bu = dl * xv * B_p[l];
        h = fmaf(a, h, bu);
        float p = h * C_p[l];
        p += __shfl_xor(p, 1, 64);
        p += __shfl_xor(p, 2, 64);
        p += __shfl_xor(p, 4, 64);
        p += __shfl_xor(p, 8, 64);
        if (n == 0) {
            const float zv = zy_p[l];
            const float gate = zv / (1.f + __expf(-zv));
            zy_p[l] = (p + Dd * xv) * gate;
        }
    }
}

extern "C" void kernel_launch(void* const* d_in, const int* in_sizes, int n_in,
                              void* d_out, int out_size, void* d_ws, size_t ws_size,
                              hipStream_t stream)
{
    (void)in_sizes; (void)n_in; (void)out_size; (void)ws_size;
    auto fp = [&](int i) { return (const float*)d_in[i]; };
    const float *pan = fp(0), *ms = fp(1);
    const float *nwp = fp(2), *nbp = fp(3), *nwm = fp(4), *nbm = fp(5);
    const float *Winp = fp(6), *Winm = fp(7), *Wzp = fp(8), *Wzm = fp(9);
    const float *cwp = fp(10), *cbp = fp(11), *cwm = fp(12), *cbm = fp(13);
    const float *Wxp = fp(14), *Wxm = fp(15);
    const float *Wdtp = fp(16), *Wdtm = fp(17), *bdtp = fp(18), *bdtm = fp(19);
    const float *Alog = fp(20), *Dp = fp(21), *Dm = fp(22);
    const float *Woutp = fp(23), *Woutm = fp(24);

    float* ws = (float*)d_ws;
    float* x3   = ws;                          // NZ*CC*LL  = 2,097,152 f
    float* xpre = x3 + (size_t)NZ * CC * LL;   // NZ*DI*LL  = 4,194,304 f (later reused as delta)
    float* zy   = xpre + (size_t)NZ * DI * LL; // NZ*DI*LL  (z, then y in place)
    float* xcv  = zy + (size_t)NZ * DI * LL;   // NZ*DI*LL  (conv output)
    float* xdbl = xcv + (size_t)NZ * DI * LL;  // NZ*DX*LL  = 655,360 f
    float* delta = xpre;                       // alias: xpre dead after conv
    float* out = (float*)d_out;

    layernorm_kernel<<<dim3(LL / 64, NZ), 256, 0, stream>>>(pan, ms, nwp, nbp, nwm, nbm, x3);
    gemm_kernel<<<dim3(LL / 64, DI / 64, NZ), 256, 0, stream>>>(Winp, Winm, x3, xpre, DI, CC, LL);
    gemm_kernel<<<dim3(LL / 64, DI / 64, NZ), 256, 0, stream>>>(Wzp, Wzm, x3, zy, DI, CC, LL);
    conv_silu_kernel<<<dim3(NZ * DI * (LL / 4) / 256), 256, 0, stream>>>(xpre, cwp, cbp, cwm, cbm, xcv);
    gemm_kernel<<<dim3(LL / 64, 1, NZ), 256, 0, stream>>>(Wxp, Wxm, xcv, xdbl, DX, DI, LL);
    delta_kernel<<<dim3(NZ * DI * (LL / 4) / 256), 256, 0, stream>>>(xdbl, Wdtp, bdtp, Wdtm, bdtm, delta);
    scan_kernel<<<dim3(NZ * DI * DS / 64), 64, 0, stream>>>(delta, xcv, xdbl, Alog, Dp, Dm, zy);
    gemm_kernel<<<dim3(LL / 64, CC / 64, NZ), 256, 0, stream>>>(Woutp, Woutm, zy, out, CC, DI, LL);
}

// Round 3
// 462.203 us; speedup vs baseline: 4.0561x; 4.0561x over previous
//
#include <hip/hip_runtime.h>
#include <hip/hip_bf16.h>

// Problem constants
constexpr int BB = 2;        // batch
constexpr int CC = 128;      // channels
constexpr int LL = 4096;     // H*W sequence length
constexpr int DI = 256;      // d_inner
constexpr int DS = 16;       // d_state
constexpr int DR = 8;        // dt_rank
constexpr int DX = 40;       // dt_rank + 2*d_state
constexpr int NZ = 2 * BB;   // branches * batch (flattened "zi" index: br*BB + b)
constexpr int CH = 32;       // scan chunk length
constexpr int NCH = LL / CH; // 128 chunks

// ---------------- LayerNorm over C, keep (zi, C, L) layout ----------------
__global__ __launch_bounds__(256) void layernorm_kernel(
    const float* __restrict__ pan, const float* __restrict__ ms,
    const float* __restrict__ wpan, const float* __restrict__ bpan,
    const float* __restrict__ wms, const float* __restrict__ bms,
    float* __restrict__ x3)
{
    const int zi = blockIdx.y;
    const int br = zi >> 1, b = zi & 1;
    const float* inp = br ? ms : pan;
    const float* wp = br ? wms : wpan;
    const float* bp = br ? bms : bpan;
    const int l0 = blockIdx.x * 64;
    const int t = threadIdx.x;
    const int lo = t & 63, c4 = t >> 6;   // c4 in 0..3, each owns 32 channels
    const float* base = inp + (size_t)b * CC * LL + l0 + lo;
    float vals[32];
    float s = 0.f, s2 = 0.f;
    #pragma unroll
    for (int i = 0; i < 32; i++) {
        const int c = c4 * 32 + i;
        const float v = base[(size_t)c * LL];
        vals[i] = v; s += v; s2 += v * v;
    }
    __shared__ float red[2][4][64];
    red[0][c4][lo] = s; red[1][c4][lo] = s2;
    __syncthreads();
    const float S  = red[0][0][lo] + red[0][1][lo] + red[0][2][lo] + red[0][3][lo];
    const float S2 = red[1][0][lo] + red[1][1][lo] + red[1][2][lo] + red[1][3][lo];
    const float mu = S * (1.f / CC);
    const float var = S2 * (1.f / CC) - mu * mu;
    const float rstd = rsqrtf(var + 1e-5f);
    float* out = x3 + (size_t)zi * CC * LL + l0 + lo;
    #pragma unroll
    for (int i = 0; i < 32; i++) {
        const int c = c4 * 32 + i;
        out[(size_t)c * LL] = (vals[i] - mu) * rstd * wp[c] + bp[c];
    }
}

// ---------------- Generic GEMM: out[zi,m,n] = sum_k W[m,k] * X[zi,k,n] --------
__global__ __launch_bounds__(256) void gemm_kernel(
    const float* __restrict__ W0, const float* __restrict__ W1,
    const float* __restrict__ X, float* __restrict__ outp,
    const int M, const int K, const int N)
{
    const int zi = blockIdx.z;
    const float* Wm = (zi >= BB) ? W1 : W0;
    const float* Xb = X + (size_t)zi * K * N;
    const int m0 = blockIdx.y * 64, n0 = blockIdx.x * 64;
    const int t = threadIdx.x;
    const int tx = t & 15, ty = t >> 4;
    __shared__ float Ws[16][65];
    __shared__ float Xs[16][64];
    float acc[4][4] = {};
    for (int k0 = 0; k0 < K; k0 += 16) {
        #pragma unroll
        for (int i = 0; i < 4; i++) {
            const int m = (t >> 4) + 16 * i;
            const int gm = m0 + m;
            float v = 0.f;
            if (gm < M) v = Wm[(size_t)gm * K + k0 + (t & 15)];
            Ws[t & 15][m] = v;
        }
        #pragma unroll
        for (int i = 0; i < 4; i++) {
            const int k = (t >> 6) + 4 * i;
            Xs[k][t & 63] = Xb[(size_t)(k0 + k) * N + n0 + (t & 63)];
        }
        __syncthreads();
        #pragma unroll
        for (int kk = 0; kk < 16; kk++) {
            float a[4], bv[4];
            #pragma unroll
            for (int i = 0; i < 4; i++) a[i] = Ws[kk][ty * 4 + i];
            #pragma unroll
            for (int j = 0; j < 4; j++) bv[j] = Xs[kk][tx * 4 + j];
            #pragma unroll
            for (int i = 0; i < 4; i++)
                #pragma unroll
                for (int j = 0; j < 4; j++)
                    acc[i][j] = fmaf(a[i], bv[j], acc[i][j]);
        }
        __syncthreads();
    }
    #pragma unroll
    for (int i = 0; i < 4; i++) {
        const int gm = m0 + ty * 4 + i;
        if (gm >= M) break;
        const size_t base = (size_t)zi * M * N + (size_t)gm * N + n0 + tx * 4;
        #pragma unroll
        for (int j = 0; j < 4; j++) outp[base + j] = acc[i][j];
    }
}

// ---------------- Causal depthwise conv (k=4) + SiLU ----------------
__global__ __launch_bounds__(256) void conv_silu_kernel(
    const float* __restrict__ xpre,
    const float* __restrict__ cw0, const float* __restrict__ cb0,
    const float* __restrict__ cw1, const float* __restrict__ cb1,
    float* __restrict__ xc)
{
    const int gid = blockIdx.x * 256 + threadIdx.x;
    const int l4 = gid & (LL / 4 - 1);
    const int e = (gid >> 10) & (DI - 1);
    const int zi = gid >> 18;
    const float* cw = (zi >= BB) ? cw1 : cw0;
    const float* cb = (zi >= BB) ? cb1 : cb0;
    const float w0 = cw[e * 4 + 0], w1 = cw[e * 4 + 1];
    const float w2 = cw[e * 4 + 2], w3 = cw[e * 4 + 3];
    const float bias = cb[e];
    const float* xp = xpre + ((size_t)zi * DI + e) * LL;
    float* op = xc + ((size_t)zi * DI + e) * LL;
    const int l0 = l4 * 4;
    float xm3, xm2, xm1;
    if (l0 == 0) { xm3 = 0.f; xm2 = 0.f; xm1 = 0.f; }
    else { xm3 = xp[l0 - 3]; xm2 = xp[l0 - 2]; xm1 = xp[l0 - 1]; }
    const float4 xv = *(const float4*)(xp + l0);
    float o0 = w0 * xm3 + w1 * xm2 + w2 * xm1 + w3 * xv.x + bias;
    float o1 = w0 * xm2 + w1 * xm1 + w2 * xv.x + w3 * xv.y + bias;
    float o2 = w0 * xm1 + w1 * xv.x + w2 * xv.y + w3 * xv.z + bias;
    float o3 = w0 * xv.x + w1 * xv.y + w2 * xv.z + w3 * xv.w + bias;
    float4 r;
    r.x = o0 / (1.f + __expf(-o0));
    r.y = o1 / (1.f + __expf(-o1));
    r.z = o2 / (1.f + __expf(-o2));
    r.w = o3 / (1.f + __expf(-o3));
    *(float4*)(op + l0) = r;
}

__device__ __forceinline__ float softplusf(float x) {
    return (x > 20.f) ? x : log1pf(__expf(x));
}

// ---------------- delta = softplus(W_dt @ dt_low + b_dt) ----------------
__global__ __launch_bounds__(256) void delta_kernel(
    const float* __restrict__ xdbl,
    const float* __restrict__ Wdt0, const float* __restrict__ bdt0,
    const float* __restrict__ Wdt1, const float* __restrict__ bdt1,
    float* __restrict__ delta)
{
    const int gid = blockIdx.x * 256 + threadIdx.x;
    const int l4 = gid & (LL / 4 - 1);
    const int e = (gid >> 10) & (DI - 1);
    const int zi = gid >> 18;
    const float* Wdt = (zi >= BB) ? Wdt1 : Wdt0;
    const float* bdt = (zi >= BB) ? bdt1 : bdt0;
    const float bias = bdt[e];
    const float* xb = xdbl + (size_t)zi * DX * LL;
    const int l0 = l4 * 4;
    float a0 = bias, a1 = bias, a2 = bias, a3 = bias;
    #pragma unroll
    for (int r = 0; r < DR; r++) {
        const float w = Wdt[e * DR + r];
        const float4 v = *(const float4*)(xb + (size_t)r * LL + l0);
        a0 = fmaf(w, v.x, a0); a1 = fmaf(w, v.y, a1);
        a2 = fmaf(w, v.z, a2); a3 = fmaf(w, v.w, a3);
    }
    float4 r4;
    r4.x = softplusf(a0); r4.y = softplusf(a1);
    r4.z = softplusf(a2); r4.w = softplusf(a3);
    *(float4*)(delta + ((size_t)zi * DI + e) * LL + l0) = r4;
}

// ================= Chunked selective scan =================
// Recurrence per (zi,d,n):  h_l = exp(dl_l*A_n)*h_{l-1} + dl_l*x_l*B_{n,l}
// Chunk decay:  prod_l exp(dl_l*A_n) = exp(A_n * sum_l dl_l)
//
// part1: thread = (zi,d,chunk); all 16 n-states in registers.
//        Writes S[(zi,d,c),n] (local scan, h_in=0) and sumdl[(zi,d,c)].
__global__ __launch_bounds__(256) void scan_part1(
    const float* __restrict__ delta, const float* __restrict__ xc,
    const float* __restrict__ xdbl, const float* __restrict__ A_log,
    float* __restrict__ Ssum, float* __restrict__ sumdl)
{
    const int tid = blockIdx.x * 256 + threadIdx.x;   // (zi*DI+d)*NCH + c
    const int c = tid & (NCH - 1);
    const int d = (tid >> 7) & (DI - 1);
    const int zi = tid >> 15;
    const float* dl_p = delta + ((size_t)zi * DI + d) * LL + c * CH;
    const float* x_p  = xc    + ((size_t)zi * DI + d) * LL + c * CH;
    const float* B_p  = xdbl + (size_t)zi * DX * LL + (size_t)DR * LL + c * CH;
    float An[DS], h[DS];
    #pragma unroll
    for (int n = 0; n < DS; n++) { An[n] = -__expf(A_log[d * DS + n]); h[n] = 0.f; }
    float sdl = 0.f;
    for (int l0 = 0; l0 < CH; l0 += 4) {
        const float4 dl4 = *(const float4*)(dl_p + l0);
        const float4 xv4 = *(const float4*)(x_p + l0);
        sdl += (dl4.x + dl4.y) + (dl4.z + dl4.w);
        const float bx0 = dl4.x * xv4.x, bx1 = dl4.y * xv4.y;
        const float bx2 = dl4.z * xv4.z, bx3 = dl4.w * xv4.w;
        #pragma unroll
        for (int n = 0; n < DS; n++) {
            const float4 B4 = *(const float4*)(B_p + (size_t)n * LL + l0);
            float hn = h[n];
            hn = fmaf(__expf(dl4.x * An[n]), hn, bx0 * B4.x);
            hn = fmaf(__expf(dl4.y * An[n]), hn, bx1 * B4.y);
            hn = fmaf(__expf(dl4.z * An[n]), hn, bx2 * B4.z);
            hn = fmaf(__expf(dl4.w * An[n]), hn, bx3 * B4.w);
            h[n] = hn;
        }
    }
    const size_t sbase = (size_t)tid * DS;
    #pragma unroll
    for (int n = 0; n < DS; n++) Ssum[sbase + n] = h[n];
    sumdl[tid] = sdl;
}

// part2: thread = (zi,d,n); serial over NCH chunk summaries.
//        hin[(zi,d,c),n] = state at chunk entry.
__global__ __launch_bounds__(256) void scan_part2(
    const float* __restrict__ Ssum, const float* __restrict__ sumdl,
    const float* __restrict__ A_log, float* __restrict__ hin)
{
    const int tid = blockIdx.x * 256 + threadIdx.x;   // (zi*DI+d)*DS + n
    const int n = tid & (DS - 1);
    const int d = (tid >> 4) & (DI - 1);
    const int zi = tid >> 12;
    const float An = -__expf(A_log[d * DS + n]);
    const size_t base = ((size_t)(zi * DI + d) * NCH) * DS + n;
    const size_t dbase = (size_t)(zi * DI + d) * NCH;
    float h = 0.f;
    for (int c = 0; c < NCH; c++) {
        hin[base + (size_t)c * DS] = h;
        const float p = __expf(An * sumdl[dbase + c]);
        h = fmaf(p, h, Ssum[base + (size_t)c * DS]);
    }
}

// part3: thread = (zi,d,chunk); re-scan from hin, y = sum_n h*C,
//        fuse D-skip + SiLU(z) gate; zy (holds z) overwritten with y_gated.
__global__ __launch_bounds__(256) void scan_part3(
    const float* __restrict__ delta, const float* __restrict__ xc,
    const float* __restrict__ xdbl, const float* __restrict__ A_log,
    const float* __restrict__ hin,
    const float* __restrict__ D0, const float* __restrict__ D1,
    float* __restrict__ zy)
{
    const int tid = blockIdx.x * 256 + threadIdx.x;
    const int c = tid & (NCH - 1);
    const int d = (tid >> 7) & (DI - 1);
    const int zi = tid >> 15;
    const float* dl_p = delta + ((size_t)zi * DI + d) * LL + c * CH;
    const float* x_p  = xc    + ((size_t)zi * DI + d) * LL + c * CH;
    const float* B_p  = xdbl + (size_t)zi * DX * LL + (size_t)DR * LL + c * CH;
    const float* C_p  = B_p + (size_t)DS * LL;
    float* zy_p = zy + ((size_t)zi * DI + d) * LL + c * CH;
    const float Dd = ((zi >= BB) ? D1 : D0)[d];
    float An[DS], h[DS];
    const size_t hbase = (size_t)tid * DS;
    #pragma unroll
    for (int n = 0; n < DS; n++) {
        An[n] = -__expf(A_log[d * DS + n]);
        h[n] = hin[hbase + n];
    }
    for (int l0 = 0; l0 < CH; l0 += 4) {
        const float4 dl4 = *(const float4*)(dl_p + l0);
        const float4 xv4 = *(const float4*)(x_p + l0);
        const float4 z4  = *(const float4*)(zy_p + l0);
        const float bx0 = dl4.x * xv4.x, bx1 = dl4.y * xv4.y;
        const float bx2 = dl4.z * xv4.z, bx3 = dl4.w * xv4.w;
        float y0 = 0.f, y1 = 0.f, y2 = 0.f, y3 = 0.f;
        #pragma unroll
        for (int n = 0; n < DS; n++) {
            const float4 B4 = *(const float4*)(B_p + (size_t)n * LL + l0);
            const float4 C4 = *(const float4*)(C_p + (size_t)n * LL + l0);
            float hn = h[n];
            hn = fmaf(__expf(dl4.x * An[n]), hn, bx0 * B4.x); y0 = fmaf(hn, C4.x, y0);
            hn = fmaf(__expf(dl4.y * An[n]), hn, bx1 * B4.y); y1 = fmaf(hn, C4.y, y1);
            hn = fmaf(__expf(dl4.z * An[n]), hn, bx2 * B4.z); y2 = fmaf(hn, C4.z, y2);
            hn = fmaf(__expf(dl4.w * An[n]), hn, bx3 * B4.w); y3 = fmaf(hn, C4.w, y3);
            h[n] = hn;
        }
        float4 r;
        y0 = fmaf(Dd, xv4.x, y0); y1 = fmaf(Dd, xv4.y, y1);
        y2 = fmaf(Dd, xv4.z, y2); y3 = fmaf(Dd, xv4.w, y3);
        r.x = y0 * (z4.x / (1.f + __expf(-z4.x)));
        r.y = y1 * (z4.y / (1.f + __expf(-z4.y)));
        r.z = y2 * (z4.z / (1.f + __expf(-z4.z)));
        r.w = y3 * (z4.w / (1.f + __expf(-z4.w)));
        *(float4*)(zy_p + l0) = r;
    }
}

extern "C" void kernel_launch(void* const* d_in, const int* in_sizes, int n_in,
                              void* d_out, int out_size, void* d_ws, size_t ws_size,
                              hipStream_t stream)
{
    (void)in_sizes; (void)n_in; (void)out_size; (void)ws_size;
    auto fp = [&](int i) { return (const float*)d_in[i]; };
    const float *pan = fp(0), *ms = fp(1);
    const float *nwp = fp(2), *nbp = fp(3), *nwm = fp(4), *nbm = fp(5);
    const float *Winp = fp(6), *Winm = fp(7), *Wzp = fp(8), *Wzm = fp(9);
    const float *cwp = fp(10), *cbp = fp(11), *cwm = fp(12), *cbm = fp(13);
    const float *Wxp = fp(14), *Wxm = fp(15);
    const float *Wdtp = fp(16), *Wdtm = fp(17), *bdtp = fp(18), *bdtm = fp(19);
    const float *Alog = fp(20), *Dp = fp(21), *Dm = fp(22);
    const float *Woutp = fp(23), *Woutm = fp(24);

    float* ws = (float*)d_ws;
    float* x3   = ws;                          // NZ*CC*LL  = 2,097,152 f
    float* xpre = x3 + (size_t)NZ * CC * LL;   // NZ*DI*LL  = 4,194,304 f (reused as delta)
    float* zy   = xpre + (size_t)NZ * DI * LL; // NZ*DI*LL  (z, then y in place)
    float* xcv  = zy + (size_t)NZ * DI * LL;   // NZ*DI*LL  (conv output)
    float* xdbl = xcv + (size_t)NZ * DI * LL;  // NZ*DX*LL  = 655,360 f
    float* Ssum = xdbl + (size_t)NZ * DX * LL; // NZ*DI*NCH*DS = 2,097,152 f
    float* sumdl = Ssum + (size_t)NZ * DI * NCH * DS; // NZ*DI*NCH = 131,072 f
    float* hin  = sumdl + (size_t)NZ * DI * NCH;      // NZ*DI*NCH*DS
    float* delta = xpre;                       // alias: xpre dead after conv
    float* out = (float*)d_out;

    layernorm_kernel<<<dim3(LL / 64, NZ), 256, 0, stream>>>(pan, ms, nwp, nbp, nwm, nbm, x3);
    gemm_kernel<<<dim3(LL / 64, DI / 64, NZ), 256, 0, stream>>>(Winp, Winm, x3, xpre, DI, CC, LL);
    gemm_kernel<<<dim3(LL / 64, DI / 64, NZ), 256, 0, stream>>>(Wzp, Wzm, x3, zy, DI, CC, LL);
    conv_silu_kernel<<<dim3(NZ * DI * (LL / 4) / 256), 256, 0, stream>>>(xpre, cwp, cbp, cwm, cbm, xcv);
    gemm_kernel<<<dim3(LL / 64, 1, NZ), 256, 0, stream>>>(Wxp, Wxm, xcv, xdbl, DX, DI, LL);
    delta_kernel<<<dim3(NZ * DI * (LL / 4) / 256), 256, 0, stream>>>(xdbl, Wdtp, bdtp, Wdtm, bdtm, delta);
    scan_part1<<<dim3(NZ * DI * NCH / 256), 256, 0, stream>>>(delta, xcv, xdbl, Alog, Ssum, sumdl);
    scan_part2<<<dim3(NZ * DI * DS / 256), 256, 0, stream>>>(Ssum, sumdl, Alog, hin);
    scan_part3<<<dim3(NZ * DI * NCH / 256), 256, 0, stream>>>(delta, xcv, xdbl, Alog, hin, Dp, Dm, zy);
    gemm_kernel<<<dim3(LL / 64, CC / 64, NZ), 256, 0, stream>>>(Woutp, Woutm, zy, out, CC, DI, LL);
}

// Round 4
// 301.173 us; speedup vs baseline: 6.2247x; 1.5347x over previous
//
#include <hip/hip_runtime.h>
#include <hip/hip_bf16.h>

// Problem constants
constexpr int BB = 2;        // batch
constexpr int CC = 128;      // channels
constexpr int LL = 4096;     // H*W sequence length
constexpr int DI = 256;      // d_inner
constexpr int DS = 16;       // d_state
constexpr int DR = 8;        // dt_rank
constexpr int DX = 40;       // dt_rank + 2*d_state
constexpr int NZ = 2 * BB;   // branches * batch
constexpr int CH = 16;       // scan chunk length (= LL/NCH)
constexpr int NCH = LL / CH; // 256 chunks == threads per scan WG

// Chunk-transposed LDS index: element (i in chunk, chunk c) -> word.
// Reads (fixed i, lane=c): bank = bijection of lane -> conflict-free.
// Staging writes (4 consecutive l per thread): 2-way -> free.
__device__ __forceinline__ int SIDX(int i, int c) {
    return i * NCH + (c ^ (((i >> 2) & 3) << 3));
}

// ---------------- LayerNorm over C, keep (zi, C, L) layout ----------------
__global__ __launch_bounds__(256) void layernorm_kernel(
    const float* __restrict__ pan, const float* __restrict__ ms,
    const float* __restrict__ wpan, const float* __restrict__ bpan,
    const float* __restrict__ wms, const float* __restrict__ bms,
    float* __restrict__ x3)
{
    const int zi = blockIdx.y;
    const int br = zi >> 1, b = zi & 1;
    const float* inp = br ? ms : pan;
    const float* wp = br ? wms : wpan;
    const float* bp = br ? bms : bpan;
    const int l0 = blockIdx.x * 64;
    const int t = threadIdx.x;
    const int lo = t & 63, c4 = t >> 6;
    const float* base = inp + (size_t)b * CC * LL + l0 + lo;
    float vals[32];
    float s = 0.f, s2 = 0.f;
    #pragma unroll
    for (int i = 0; i < 32; i++) {
        const int c = c4 * 32 + i;
        const float v = base[(size_t)c * LL];
        vals[i] = v; s += v; s2 += v * v;
    }
    __shared__ float red[2][4][64];
    red[0][c4][lo] = s; red[1][c4][lo] = s2;
    __syncthreads();
    const float S  = red[0][0][lo] + red[0][1][lo] + red[0][2][lo] + red[0][3][lo];
    const float S2 = red[1][0][lo] + red[1][1][lo] + red[1][2][lo] + red[1][3][lo];
    const float mu = S * (1.f / CC);
    const float var = S2 * (1.f / CC) - mu * mu;
    const float rstd = rsqrtf(var + 1e-5f);
    float* out = x3 + (size_t)zi * CC * LL + l0 + lo;
    #pragma unroll
    for (int i = 0; i < 32; i++) {
        const int c = c4 * 32 + i;
        out[(size_t)c * LL] = (vals[i] - mu) * rstd * wp[c] + bp[c];
    }
}

// ---------------- Generic GEMM: out[zi,m,n] = sum_k W[m,k] * X[zi,k,n] --------
__global__ __launch_bounds__(256) void gemm_kernel(
    const float* __restrict__ W0, const float* __restrict__ W1,
    const float* __restrict__ X, float* __restrict__ outp,
    const int M, const int K, const int N)
{
    const int zi = blockIdx.z;
    const float* Wm = (zi >= BB) ? W1 : W0;
    const float* Xb = X + (size_t)zi * K * N;
    const int m0 = blockIdx.y * 64, n0 = blockIdx.x * 64;
    const int t = threadIdx.x;
    const int tx = t & 15, ty = t >> 4;
    __shared__ float Ws[16][68];   // pad 68: rows 16B-aligned, 2-way write conflicts only
    __shared__ float Xs[16][64];
    float acc[4][4] = {};
    for (int k0 = 0; k0 < K; k0 += 16) {
        #pragma unroll
        for (int i = 0; i < 4; i++) {
            const int m = (t >> 4) + 16 * i;
            const int gm = m0 + m;
            float v = 0.f;
            if (gm < M) v = Wm[(size_t)gm * K + k0 + (t & 15)];
            Ws[t & 15][m] = v;
        }
        #pragma unroll
        for (int i = 0; i < 4; i++) {
            const int k = (t >> 6) + 4 * i;
            Xs[k][t & 63] = Xb[(size_t)(k0 + k) * N + n0 + (t & 63)];
        }
        __syncthreads();
        #pragma unroll
        for (int kk = 0; kk < 16; kk++) {
            const float4 av = *(const float4*)(&Ws[kk][ty * 4]);
            const float4 bv = *(const float4*)(&Xs[kk][tx * 4]);
            acc[0][0] = fmaf(av.x, bv.x, acc[0][0]);
            acc[0][1] = fmaf(av.x, bv.y, acc[0][1]);
            acc[0][2] = fmaf(av.x, bv.z, acc[0][2]);
            acc[0][3] = fmaf(av.x, bv.w, acc[0][3]);
            acc[1][0] = fmaf(av.y, bv.x, acc[1][0]);
            acc[1][1] = fmaf(av.y, bv.y, acc[1][1]);
            acc[1][2] = fmaf(av.y, bv.z, acc[1][2]);
            acc[1][3] = fmaf(av.y, bv.w, acc[1][3]);
            acc[2][0] = fmaf(av.z, bv.x, acc[2][0]);
            acc[2][1] = fmaf(av.z, bv.y, acc[2][1]);
            acc[2][2] = fmaf(av.z, bv.z, acc[2][2]);
            acc[2][3] = fmaf(av.z, bv.w, acc[2][3]);
            acc[3][0] = fmaf(av.w, bv.x, acc[3][0]);
            acc[3][1] = fmaf(av.w, bv.y, acc[3][1]);
            acc[3][2] = fmaf(av.w, bv.z, acc[3][2]);
            acc[3][3] = fmaf(av.w, bv.w, acc[3][3]);
        }
        __syncthreads();
    }
    #pragma unroll
    for (int i = 0; i < 4; i++) {
        const int gm = m0 + ty * 4 + i;
        if (gm >= M) break;
        const size_t base = (size_t)zi * M * N + (size_t)gm * N + n0 + tx * 4;
        #pragma unroll
        for (int j = 0; j < 4; j++) outp[base + j] = acc[i][j];
    }
}

// ---------------- Causal depthwise conv (k=4) + SiLU ----------------
__global__ __launch_bounds__(256) void conv_silu_kernel(
    const float* __restrict__ xpre,
    const float* __restrict__ cw0, const float* __restrict__ cb0,
    const float* __restrict__ cw1, const float* __restrict__ cb1,
    float* __restrict__ xc)
{
    const int gid = blockIdx.x * 256 + threadIdx.x;
    const int l4 = gid & (LL / 4 - 1);
    const int e = (gid >> 10) & (DI - 1);
    const int zi = gid >> 18;
    const float* cw = (zi >= BB) ? cw1 : cw0;
    const float* cb = (zi >= BB) ? cb1 : cb0;
    const float w0 = cw[e * 4 + 0], w1 = cw[e * 4 + 1];
    const float w2 = cw[e * 4 + 2], w3 = cw[e * 4 + 3];
    const float bias = cb[e];
    const float* xp = xpre + ((size_t)zi * DI + e) * LL;
    float* op = xc + ((size_t)zi * DI + e) * LL;
    const int l0 = l4 * 4;
    float xm3, xm2, xm1;
    if (l0 == 0) { xm3 = 0.f; xm2 = 0.f; xm1 = 0.f; }
    else { xm3 = xp[l0 - 3]; xm2 = xp[l0 - 2]; xm1 = xp[l0 - 1]; }
    const float4 xv = *(const float4*)(xp + l0);
    float o0 = w0 * xm3 + w1 * xm2 + w2 * xm1 + w3 * xv.x + bias;
    float o1 = w0 * xm2 + w1 * xm1 + w2 * xv.x + w3 * xv.y + bias;
    float o2 = w0 * xm1 + w1 * xv.x + w2 * xv.y + w3 * xv.z + bias;
    float o3 = w0 * xv.x + w1 * xv.y + w2 * xv.z + w3 * xv.w + bias;
    float4 r;
    r.x = o0 / (1.f + __expf(-o0));
    r.y = o1 / (1.f + __expf(-o1));
    r.z = o2 / (1.f + __expf(-o2));
    r.w = o3 / (1.f + __expf(-o3));
    *(float4*)(op + l0) = r;
}

__device__ __forceinline__ float softplusf(float x) {
    return (x > 20.f) ? x : log1pf(__expf(x));
}

// ---------------- delta = softplus(W_dt @ dt_low + b_dt) ----------------
__global__ __launch_bounds__(256) void delta_kernel(
    const float* __restrict__ xdbl,
    const float* __restrict__ Wdt0, const float* __restrict__ bdt0,
    const float* __restrict__ Wdt1, const float* __restrict__ bdt1,
    float* __restrict__ delta)
{
    const int gid = blockIdx.x * 256 + threadIdx.x;
    const int l4 = gid & (LL / 4 - 1);
    const int e = (gid >> 10) & (DI - 1);
    const int zi = gid >> 18;
    const float* Wdt = (zi >= BB) ? Wdt1 : Wdt0;
    const float* bdt = (zi >= BB) ? bdt1 : bdt0;
    const float bias = bdt[e];
    const float* xb = xdbl + (size_t)zi * DX * LL;
    const int l0 = l4 * 4;
    float a0 = bias, a1 = bias, a2 = bias, a3 = bias;
    #pragma unroll
    for (int r = 0; r < DR; r++) {
        const float w = Wdt[e * DR + r];
        const float4 v = *(const float4*)(xb + (size_t)r * LL + l0);
        a0 = fmaf(w, v.x, a0); a1 = fmaf(w, v.y, a1);
        a2 = fmaf(w, v.z, a2); a3 = fmaf(w, v.w, a3);
    }
    float4 r4;
    r4.x = softplusf(a0); r4.y = softplusf(a1);
    r4.z = softplusf(a2); r4.w = softplusf(a3);
    *(float4*)(delta + ((size_t)zi * DI + e) * LL + l0) = r4;
}

// ================= Chunked selective scan (coalesced) =================
// WG = one (zi,d) row; thread t = chunk t (CH=16).  Rows staged cooperatively
// (coalesced float4 global loads) into chunk-transposed swizzled LDS.

// part1: local scans -> Ssum[(zi,d)][n][c] (coalesced) + sumdl[(zi,d)][c]
__global__ __launch_bounds__(256) void scan_part1(
    const float* __restrict__ delta, const float* __restrict__ xc,
    const float* __restrict__ xdbl, const float* __restrict__ A_log,
    float* __restrict__ Ssum, float* __restrict__ sumdl)
{
    const int blk = blockIdx.x;          // zi*DI + d
    const int zi = blk >> 8;
    const int d  = blk & (DI - 1);
    const int t = threadIdx.x;
    __shared__ float s[2][LL];
    const float* dl_g = delta + (size_t)blk * LL;
    const float* x_g  = xc + (size_t)blk * LL;
    #pragma unroll
    for (int j = 0; j < 4; j++) {
        const int idx = (j * 256 + t) * 4;
        const float4 dv = *(const float4*)(dl_g + idx);
        const float4 xv = *(const float4*)(x_g + idx);
        const int c = idx >> 4;
        const int ib = idx & 15;
        s[0][SIDX(ib + 0, c)] = dv.x; s[0][SIDX(ib + 1, c)] = dv.y;
        s[0][SIDX(ib + 2, c)] = dv.z; s[0][SIDX(ib + 3, c)] = dv.w;
        s[1][SIDX(ib + 0, c)] = xv.x; s[1][SIDX(ib + 1, c)] = xv.y;
        s[1][SIDX(ib + 2, c)] = xv.z; s[1][SIDX(ib + 3, c)] = xv.w;
    }
    __syncthreads();
    float rdl[CH], rdlx[CH];
    float sdl = 0.f;
    #pragma unroll
    for (int i = 0; i < CH; i++) {
        rdl[i] = s[0][SIDX(i, t)];
        rdlx[i] = rdl[i] * s[1][SIDX(i, t)];
        sdl += rdl[i];
    }
    sumdl[(size_t)blk * NCH + t] = sdl;
    __syncthreads();
    const float* Bbase = xdbl + (size_t)zi * DX * LL + (size_t)DR * LL;
    // prefetch B row 0 into s[0]
    #pragma unroll
    for (int j = 0; j < 4; j++) {
        const int idx = (j * 256 + t) * 4;
        const float4 bv = *(const float4*)(Bbase + idx);
        const int c = idx >> 4, ib = idx & 15;
        s[0][SIDX(ib + 0, c)] = bv.x; s[0][SIDX(ib + 1, c)] = bv.y;
        s[0][SIDX(ib + 2, c)] = bv.z; s[0][SIDX(ib + 3, c)] = bv.w;
    }
    __syncthreads();
    for (int n = 0; n < DS; n++) {
        if (n < DS - 1) {   // stage next B row into the other buffer
            const float* Bn = Bbase + (size_t)(n + 1) * LL;
            float* dst = s[(n + 1) & 1];
            #pragma unroll
            for (int j = 0; j < 4; j++) {
                const int idx = (j * 256 + t) * 4;
                const float4 bv = *(const float4*)(Bn + idx);
                const int c = idx >> 4, ib = idx & 15;
                dst[SIDX(ib + 0, c)] = bv.x; dst[SIDX(ib + 1, c)] = bv.y;
                dst[SIDX(ib + 2, c)] = bv.z; dst[SIDX(ib + 3, c)] = bv.w;
            }
        }
        const float An = -__expf(A_log[d * DS + n]);
        const float* sb = s[n & 1];
        float hn = 0.f;
        #pragma unroll
        for (int i = 0; i < CH; i++) {
            hn = fmaf(__expf(rdl[i] * An), hn, rdlx[i] * sb[SIDX(i, t)]);
        }
        Ssum[((size_t)blk * DS + n) * NCH + t] = hn;
        __syncthreads();
    }
}

// part2: serial over chunk summaries, IN PLACE (S becomes h_in).
__global__ __launch_bounds__(256) void scan_part2(
    float* S, const float* __restrict__ sumdl, const float* __restrict__ A_log)
{
    const int tid = blockIdx.x * 256 + threadIdx.x;  // (zi*DI+d)*DS + n
    const int n = tid & (DS - 1);
    const int row = tid >> 4;
    const int d = row & (DI - 1);
    const float An = -__expf(A_log[d * DS + n]);
    const size_t base = (size_t)tid * NCH;
    const size_t dbase = (size_t)row * NCH;
    float h = 0.f;
    for (int c = 0; c < NCH; c++) {
        const float tmp = S[base + c];
        const float p = __expf(An * sumdl[dbase + c]);
        S[base + c] = h;                 // h_in for chunk c
        h = fmaf(p, h, tmp);
    }
}

// part3: re-scan from h_in, y = sum_n h*C, fuse D-skip + SiLU(z) gate.
__global__ __launch_bounds__(256) void scan_part3(
    const float* __restrict__ delta, const float* __restrict__ xc,
    const float* __restrict__ xdbl, const float* __restrict__ A_log,
    const float* __restrict__ hin,
    const float* __restrict__ D0, const float* __restrict__ D1,
    float* __restrict__ zy)
{
    const int blk = blockIdx.x;
    const int zi = blk >> 8;
    const int d  = blk & (DI - 1);
    const int t = threadIdx.x;
    __shared__ float s[2][LL];
    const float* dl_g = delta + (size_t)blk * LL;
    const float* x_g  = xc + (size_t)blk * LL;
    float* zy_g = zy + (size_t)blk * LL;
    #pragma unroll
    for (int j = 0; j < 4; j++) {
        const int idx = (j * 256 + t) * 4;
        const float4 dv = *(const float4*)(dl_g + idx);
        const float4 xv = *(const float4*)(x_g + idx);
        const int c = idx >> 4, ib = idx & 15;
        s[0][SIDX(ib + 0, c)] = dv.x; s[0][SIDX(ib + 1, c)] = dv.y;
        s[0][SIDX(ib + 2, c)] = dv.z; s[0][SIDX(ib + 3, c)] = dv.w;
        s[1][SIDX(ib + 0, c)] = xv.x; s[1][SIDX(ib + 1, c)] = xv.y;
        s[1][SIDX(ib + 2, c)] = xv.z; s[1][SIDX(ib + 3, c)] = xv.w;
    }
    __syncthreads();
    float rdl[CH], rdlx[CH], y[CH];
    #pragma unroll
    for (int i = 0; i < CH; i++) {
        rdl[i] = s[0][SIDX(i, t)];
        rdlx[i] = rdl[i] * s[1][SIDX(i, t)];
        y[i] = 0.f;
    }
    __syncthreads();
    const float* Bbase = xdbl + (size_t)zi * DX * LL + (size_t)DR * LL;
    const float* Cbase = Bbase + (size_t)DS * LL;
    for (int n = 0; n < DS; n++) {
        #pragma unroll
        for (int j = 0; j < 4; j++) {
            const int idx = (j * 256 + t) * 4;
            const float4 bv = *(const float4*)(Bbase + (size_t)n * LL + idx);
            const float4 cv = *(const float4*)(Cbase + (size_t)n * LL + idx);
            const int c = idx >> 4, ib = idx & 15;
            s[0][SIDX(ib + 0, c)] = bv.x; s[0][SIDX(ib + 1, c)] = bv.y;
            s[0][SIDX(ib + 2, c)] = bv.z; s[0][SIDX(ib + 3, c)] = bv.w;
            s[1][SIDX(ib + 0, c)] = cv.x; s[1][SIDX(ib + 1, c)] = cv.y;
            s[1][SIDX(ib + 2, c)] = cv.z; s[1][SIDX(ib + 3, c)] = cv.w;
        }
        __syncthreads();
        const float An = -__expf(A_log[d * DS + n]);
        float hn = hin[((size_t)blk * DS + n) * NCH + t];
        #pragma unroll
        for (int i = 0; i < CH; i++) {
            hn = fmaf(__expf(rdl[i] * An), hn, rdlx[i] * s[0][SIDX(i, t)]);
            y[i] = fmaf(hn, s[1][SIDX(i, t)], y[i]);
        }
        __syncthreads();
    }
    // stash y (chunk-transposed), then cooperative gated write-out
    #pragma unroll
    for (int i = 0; i < CH; i++) s[0][SIDX(i, t)] = y[i];
    const float Dd = ((zi >= BB) ? D1 : D0)[d];
    __syncthreads();
    #pragma unroll
    for (int j = 0; j < 4; j++) {
        const int idx = (j * 256 + t) * 4;
        const int c = idx >> 4, ib = idx & 15;
        const float4 zv = *(const float4*)(zy_g + idx);
        const float4 xv = *(const float4*)(x_g + idx);
        float4 r;
        r.x = (s[0][SIDX(ib + 0, c)] + Dd * xv.x) * (zv.x / (1.f + __expf(-zv.x)));
        r.y = (s[0][SIDX(ib + 1, c)] + Dd * xv.y) * (zv.y / (1.f + __expf(-zv.y)));
        r.z = (s[0][SIDX(ib + 2, c)] + Dd * xv.z) * (zv.z / (1.f + __expf(-zv.z)));
        r.w = (s[0][SIDX(ib + 3, c)] + Dd * xv.w) * (zv.w / (1.f + __expf(-zv.w)));
        *(float4*)(zy_g + idx) = r;
    }
}

extern "C" void kernel_launch(void* const* d_in, const int* in_sizes, int n_in,
                              void* d_out, int out_size, void* d_ws, size_t ws_size,
                              hipStream_t stream)
{
    (void)in_sizes; (void)n_in; (void)out_size; (void)ws_size;
    auto fp = [&](int i) { return (const float*)d_in[i]; };
    const float *pan = fp(0), *ms = fp(1);
    const float *nwp = fp(2), *nbp = fp(3), *nwm = fp(4), *nbm = fp(5);
    const float *Winp = fp(6), *Winm = fp(7), *Wzp = fp(8), *Wzm = fp(9);
    const float *cwp = fp(10), *cbp = fp(11), *cwm = fp(12), *cbm = fp(13);
    const float *Wxp = fp(14), *Wxm = fp(15);
    const float *Wdtp = fp(16), *Wdtm = fp(17), *bdtp = fp(18), *bdtm = fp(19);
    const float *Alog = fp(20), *Dp = fp(21), *Dm = fp(22);
    const float *Woutp = fp(23), *Woutm = fp(24);

    float* ws = (float*)d_ws;
    float* x3   = ws;                          // NZ*CC*LL
    float* xpre = x3 + (size_t)NZ * CC * LL;   // NZ*DI*LL (reused as delta)
    float* zy   = xpre + (size_t)NZ * DI * LL; // NZ*DI*LL (z, then y in place)
    float* xcv  = zy + (size_t)NZ * DI * LL;   // NZ*DI*LL (conv output)
    float* xdbl = xcv + (size_t)NZ * DI * LL;  // NZ*DX*LL
    float* Ssum = xdbl + (size_t)NZ * DX * LL; // NZ*DI*DS*NCH (in-place -> hin)
    float* sumdl = Ssum + (size_t)NZ * DI * DS * NCH; // NZ*DI*NCH
    float* delta = xpre;
    float* out = (float*)d_out;

    layernorm_kernel<<<dim3(LL / 64, NZ), 256, 0, stream>>>(pan, ms, nwp, nbp, nwm, nbm, x3);
    gemm_kernel<<<dim3(LL / 64, DI / 64, NZ), 256, 0, stream>>>(Winp, Winm, x3, xpre, DI, CC, LL);
    gemm_kernel<<<dim3(LL / 64, DI / 64, NZ), 256, 0, stream>>>(Wzp, Wzm, x3, zy, DI, CC, LL);
    conv_silu_kernel<<<dim3(NZ * DI * (LL / 4) / 256), 256, 0, stream>>>(xpre, cwp, cbp, cwm, cbm, xcv);
    gemm_kernel<<<dim3(LL / 64, 1, NZ), 256, 0, stream>>>(Wxp, Wxm, xcv, xdbl, DX, DI, LL);
    delta_kernel<<<dim3(NZ * DI * (LL / 4) / 256), 256, 0, stream>>>(xdbl, Wdtp, bdtp, Wdtm, bdtm, delta);
    scan_part1<<<dim3(NZ * DI), 256, 0, stream>>>(delta, xcv, xdbl, Alog, Ssum, sumdl);
    scan_part2<<<dim3(NZ * DI * DS / 256), 256, 0, stream>>>(Ssum, sumdl, Alog);
    scan_part3<<<dim3(NZ * DI), 256, 0, stream>>>(delta, xcv, xdbl, Alog, Ssum, Dp, Dm, zy);
    gemm_kernel<<<dim3(LL / 64, CC / 64, NZ), 256, 0, stream>>>(Woutp, Woutm, zy, out, CC, DI, LL);
}

// Round 5
// 263.468 us; speedup vs baseline: 7.1155x; 1.1431x over previous
//
#include <hip/hip_runtime.h>
#include <hip/hip_bf16.h>

// Problem constants
constexpr int BB = 2;        // batch
constexpr int CC = 128;      // channels
constexpr int LL = 4096;     // H*W sequence length
constexpr int DI = 256;      // d_inner
constexpr int DS = 16;       // d_state
constexpr int DR = 8;        // dt_rank
constexpr int DX = 40;       // dt_rank + 2*d_state
constexpr int NZ = 2 * BB;   // branches * batch
constexpr int CH = 16;       // scan chunk length (= LL/NCH)
constexpr int NCH = LL / CH; // 256 chunks == threads per scan WG

typedef short bf16x8 __attribute__((ext_vector_type(8)));
typedef float f32x4 __attribute__((ext_vector_type(4)));

__device__ __forceinline__ unsigned short f2bf(float x) {
    __hip_bfloat16 h = __float2bfloat16(x);
    return *(unsigned short*)&h;
}

// Chunk-transposed LDS index for the scan kernels.
__device__ __forceinline__ int SIDX(int i, int c) {
    return i * NCH + (c ^ (((i >> 2) & 3) << 3));
}

// ---------------- Weight fp32 -> bf16 conversion (once per call) -------------
// Segments (element offsets): Winp 0, Winm 32768, Wzp 65536, Wzm 98304,
//                             Woutp 131072, Woutm 163840; total 196608.
__global__ __launch_bounds__(256) void convert_w_kernel(
    const float* __restrict__ Winp, const float* __restrict__ Winm,
    const float* __restrict__ Wzp, const float* __restrict__ Wzm,
    const float* __restrict__ Woutp, const float* __restrict__ Woutm,
    unsigned short* __restrict__ dst)
{
    const int i = blockIdx.x * 256 + threadIdx.x;
    const float* src;
    int off;
    if (i < 65536)       { src = (i < 32768) ? Winp : Winm;   off = i & 32767;  }
    else if (i < 131072) { src = (i < 98304) ? Wzp : Wzm;     off = (i - 65536) & 32767; }
    else                 { src = (i < 163840) ? Woutp : Woutm; off = (i - 131072) & 32767; }
    dst[i] = f2bf(src[off]);
}

// ---------------- LayerNorm over C, keep (zi, C, L) layout ----------------
__global__ __launch_bounds__(256) void layernorm_kernel(
    const float* __restrict__ pan, const float* __restrict__ ms,
    const float* __restrict__ wpan, const float* __restrict__ bpan,
    const float* __restrict__ wms, const float* __restrict__ bms,
    float* __restrict__ x3)
{
    const int zi = blockIdx.y;
    const int br = zi >> 1, b = zi & 1;
    const float* inp = br ? ms : pan;
    const float* wp = br ? wms : wpan;
    const float* bp = br ? bms : bpan;
    const int l0 = blockIdx.x * 64;
    const int t = threadIdx.x;
    const int lo = t & 63, c4 = t >> 6;
    const float* base = inp + (size_t)b * CC * LL + l0 + lo;
    float vals[32];
    float s = 0.f, s2 = 0.f;
    #pragma unroll
    for (int i = 0; i < 32; i++) {
        const int c = c4 * 32 + i;
        const float v = base[(size_t)c * LL];
        vals[i] = v; s += v; s2 += v * v;
    }
    __shared__ float red[2][4][64];
    red[0][c4][lo] = s; red[1][c4][lo] = s2;
    __syncthreads();
    const float S  = red[0][0][lo] + red[0][1][lo] + red[0][2][lo] + red[0][3][lo];
    const float S2 = red[1][0][lo] + red[1][1][lo] + red[1][2][lo] + red[1][3][lo];
    const float mu = S * (1.f / CC);
    const float var = S2 * (1.f / CC) - mu * mu;
    const float rstd = rsqrtf(var + 1e-5f);
    float* out = x3 + (size_t)zi * CC * LL + l0 + lo;
    #pragma unroll
    for (int i = 0; i < 32; i++) {
        const int c = c4 * 32 + i;
        out[(size_t)c * LL] = (vals[i] - mu) * rstd * wp[c] + bp[c];
    }
}

// ================= MFMA bf16 GEMM building block =================
// out[zi, m, n] = sum_k W[m,k] * X[zi,k,n], W bf16 (k-contiguous), X fp32.
// Block: 256 thr / 4 waves; tile 64M x 64N; K-chunks of 32.
// A-frags straight from global (verified layout: m=lane&15, k=(lane>>4)*8+j).
// X tile transposed fp32->bf16 into LDS [64 n][40 k] (pair-packed writes,
// rows 80 B = 16B-aligned so B-frag is one ds_read_b128).
// C/D: col=lane&15 (n), row=(lane>>4)*4+reg (m).

// Fused W_in + W_z: M=512 logical (my 0..3 -> W_in -> xpre; 4..7 -> W_z -> zy)
__global__ __launch_bounds__(256) void gemm_inz_mfma(
    const unsigned short* __restrict__ wb, const float* __restrict__ x3,
    float* __restrict__ xpre, float* __restrict__ zy)
{
    const int zi = blockIdx.z;
    const int my = blockIdx.y;
    const unsigned short* W = wb + (my >= 4 ? 65536 : 0) + (zi >= BB ? 32768 : 0);
    float* outp = (my >= 4) ? zy : xpre;
    const int mbase = (my & 3) * 64;
    const float* Xb = x3 + (size_t)zi * CC * LL;
    const int n0 = blockIdx.x * 64;
    const int t = threadIdx.x;
    const int w = t >> 6, ln = t & 63;
    const int nf = ln & 15, qb = ln >> 4;
    // A prefetch: K=128 -> 4 chunks
    bf16x8 afrag[4];
    const int mrow = mbase + w * 16 + nf;
    #pragma unroll
    for (int c = 0; c < 4; c++)
        afrag[c] = *(const bf16x8*)(W + (size_t)mrow * CC + c * 32 + qb * 8);
    __shared__ unsigned short Bs[64][40];
    unsigned* Bw = (unsigned*)Bs;
    f32x4 acc[4] = {};
    const int kp = t >> 4, n4 = (t & 15) * 4;
    #pragma unroll
    for (int kc = 0; kc < 4; kc++) {
        const float* src = Xb + (size_t)(kc * 32 + 2 * kp) * LL + n0 + n4;
        const float4 r0 = *(const float4*)src;
        const float4 r1 = *(const float4*)(src + LL);
        if (kc) __syncthreads();
        Bw[(n4 + 0) * 20 + kp] = (unsigned)f2bf(r0.x) | ((unsigned)f2bf(r1.x) << 16);
        Bw[(n4 + 1) * 20 + kp] = (unsigned)f2bf(r0.y) | ((unsigned)f2bf(r1.y) << 16);
        Bw[(n4 + 2) * 20 + kp] = (unsigned)f2bf(r0.z) | ((unsigned)f2bf(r1.z) << 16);
        Bw[(n4 + 3) * 20 + kp] = (unsigned)f2bf(r0.w) | ((unsigned)f2bf(r1.w) << 16);
        __syncthreads();
        #pragma unroll
        for (int ns = 0; ns < 4; ns++) {
            const bf16x8 bf = *(const bf16x8*)(&Bs[ns * 16 + nf][qb * 8]);
            acc[ns] = __builtin_amdgcn_mfma_f32_16x16x32_bf16(afrag[kc], bf, acc[ns], 0, 0, 0);
        }
    }
    #pragma unroll
    for (int ns = 0; ns < 4; ns++)
        #pragma unroll
        for (int r = 0; r < 4; r++) {
            const int m = mbase + w * 16 + qb * 4 + r;
            outp[((size_t)zi * DI + m) * LL + n0 + ns * 16 + nf] = acc[ns][r];
        }
}

// W_out: M=128, K=256, writes d_out (fp32) at (zi*CC + m)*LL + n
__global__ __launch_bounds__(256) void gemm_out_mfma(
    const unsigned short* __restrict__ wb, const float* __restrict__ y,
    float* __restrict__ outg)
{
    const int zi = blockIdx.z;
    const unsigned short* W = wb + 131072 + (zi >= BB ? 32768 : 0);
    const int mbase = blockIdx.y * 64;
    const float* Xb = y + (size_t)zi * DI * LL;
    const int n0 = blockIdx.x * 64;
    const int t = threadIdx.x;
    const int w = t >> 6, ln = t & 63;
    const int nf = ln & 15, qb = ln >> 4;
    bf16x8 afrag[8];
    const int mrow = mbase + w * 16 + nf;
    #pragma unroll
    for (int c = 0; c < 8; c++)
        afrag[c] = *(const bf16x8*)(W + (size_t)mrow * DI + c * 32 + qb * 8);
    __shared__ unsigned short Bs[64][40];
    unsigned* Bw = (unsigned*)Bs;
    f32x4 acc[4] = {};
    const int kp = t >> 4, n4 = (t & 15) * 4;
    #pragma unroll
    for (int kc = 0; kc < 8; kc++) {
        const float* src = Xb + (size_t)(kc * 32 + 2 * kp) * LL + n0 + n4;
        const float4 r0 = *(const float4*)src;
        const float4 r1 = *(const float4*)(src + LL);
        if (kc) __syncthreads();
        Bw[(n4 + 0) * 20 + kp] = (unsigned)f2bf(r0.x) | ((unsigned)f2bf(r1.x) << 16);
        Bw[(n4 + 1) * 20 + kp] = (unsigned)f2bf(r0.y) | ((unsigned)f2bf(r1.y) << 16);
        Bw[(n4 + 2) * 20 + kp] = (unsigned)f2bf(r0.z) | ((unsigned)f2bf(r1.z) << 16);
        Bw[(n4 + 3) * 20 + kp] = (unsigned)f2bf(r0.w) | ((unsigned)f2bf(r1.w) << 16);
        __syncthreads();
        #pragma unroll
        for (int ns = 0; ns < 4; ns++) {
            const bf16x8 bf = *(const bf16x8*)(&Bs[ns * 16 + nf][qb * 8]);
            acc[ns] = __builtin_amdgcn_mfma_f32_16x16x32_bf16(afrag[kc], bf, acc[ns], 0, 0, 0);
        }
    }
    #pragma unroll
    for (int ns = 0; ns < 4; ns++)
        #pragma unroll
        for (int r = 0; r < 4; r++) {
            const int m = mbase + w * 16 + qb * 4 + r;
            outg[((size_t)zi * CC + m) * LL + n0 + ns * 16 + nf] = acc[ns][r];
        }
}

// ---------------- fp32 GEMM (kept for W_x: precision-critical dt path) ------
__global__ __launch_bounds__(256) void gemm_kernel(
    const float* __restrict__ W0, const float* __restrict__ W1,
    const float* __restrict__ X, float* __restrict__ outp,
    const int M, const int K, const int N)
{
    const int zi = blockIdx.z;
    const float* Wm = (zi >= BB) ? W1 : W0;
    const float* Xb = X + (size_t)zi * K * N;
    const int m0 = blockIdx.y * 64, n0 = blockIdx.x * 64;
    const int t = threadIdx.x;
    const int tx = t & 15, ty = t >> 4;
    __shared__ float Ws[16][68];
    __shared__ float Xs[16][64];
    float acc[4][4] = {};
    for (int k0 = 0; k0 < K; k0 += 16) {
        #pragma unroll
        for (int i = 0; i < 4; i++) {
            const int m = (t >> 4) + 16 * i;
            const int gm = m0 + m;
            float v = 0.f;
            if (gm < M) v = Wm[(size_t)gm * K + k0 + (t & 15)];
            Ws[t & 15][m] = v;
        }
        #pragma unroll
        for (int i = 0; i < 4; i++) {
            const int k = (t >> 6) + 4 * i;
            Xs[k][t & 63] = Xb[(size_t)(k0 + k) * N + n0 + (t & 63)];
        }
        __syncthreads();
        #pragma unroll
        for (int kk = 0; kk < 16; kk++) {
            const float4 av = *(const float4*)(&Ws[kk][ty * 4]);
            const float4 bv = *(const float4*)(&Xs[kk][tx * 4]);
            acc[0][0] = fmaf(av.x, bv.x, acc[0][0]);
            acc[0][1] = fmaf(av.x, bv.y, acc[0][1]);
            acc[0][2] = fmaf(av.x, bv.z, acc[0][2]);
            acc[0][3] = fmaf(av.x, bv.w, acc[0][3]);
            acc[1][0] = fmaf(av.y, bv.x, acc[1][0]);
            acc[1][1] = fmaf(av.y, bv.y, acc[1][1]);
            acc[1][2] = fmaf(av.y, bv.z, acc[1][2]);
            acc[1][3] = fmaf(av.y, bv.w, acc[1][3]);
            acc[2][0] = fmaf(av.z, bv.x, acc[2][0]);
            acc[2][1] = fmaf(av.z, bv.y, acc[2][1]);
            acc[2][2] = fmaf(av.z, bv.z, acc[2][2]);
            acc[2][3] = fmaf(av.z, bv.w, acc[2][3]);
            acc[3][0] = fmaf(av.w, bv.x, acc[3][0]);
            acc[3][1] = fmaf(av.w, bv.y, acc[3][1]);
            acc[3][2] = fmaf(av.w, bv.z, acc[3][2]);
            acc[3][3] = fmaf(av.w, bv.w, acc[3][3]);
        }
        __syncthreads();
    }
    #pragma unroll
    for (int i = 0; i < 4; i++) {
        const int gm = m0 + ty * 4 + i;
        if (gm >= M) break;
        const size_t base = (size_t)zi * M * N + (size_t)gm * N + n0 + tx * 4;
        #pragma unroll
        for (int j = 0; j < 4; j++) outp[base + j] = acc[i][j];
    }
}

// ---------------- Causal depthwise conv (k=4) + SiLU ----------------
__global__ __launch_bounds__(256) void conv_silu_kernel(
    const float* __restrict__ xpre,
    const float* __restrict__ cw0, const float* __restrict__ cb0,
    const float* __restrict__ cw1, const float* __restrict__ cb1,
    float* __restrict__ xc)
{
    const int gid = blockIdx.x * 256 + threadIdx.x;
    const int l4 = gid & (LL / 4 - 1);
    const int e = (gid >> 10) & (DI - 1);
    const int zi = gid >> 18;
    const float* cw = (zi >= BB) ? cw1 : cw0;
    const float* cb = (zi >= BB) ? cb1 : cb0;
    const float w0 = cw[e * 4 + 0], w1 = cw[e * 4 + 1];
    const float w2 = cw[e * 4 + 2], w3 = cw[e * 4 + 3];
    const float bias = cb[e];
    const float* xp = xpre + ((size_t)zi * DI + e) * LL;
    float* op = xc + ((size_t)zi * DI + e) * LL;
    const int l0 = l4 * 4;
    float xm3, xm2, xm1;
    if (l0 == 0) { xm3 = 0.f; xm2 = 0.f; xm1 = 0.f; }
    else { xm3 = xp[l0 - 3]; xm2 = xp[l0 - 2]; xm1 = xp[l0 - 1]; }
    const float4 xv = *(const float4*)(xp + l0);
    float o0 = w0 * xm3 + w1 * xm2 + w2 * xm1 + w3 * xv.x + bias;
    float o1 = w0 * xm2 + w1 * xm1 + w2 * xv.x + w3 * xv.y + bias;
    float o2 = w0 * xm1 + w1 * xv.x + w2 * xv.y + w3 * xv.z + bias;
    float o3 = w0 * xv.x + w1 * xv.y + w2 * xv.z + w3 * xv.w + bias;
    float4 r;
    r.x = o0 / (1.f + __expf(-o0));
    r.y = o1 / (1.f + __expf(-o1));
    r.z = o2 / (1.f + __expf(-o2));
    r.w = o3 / (1.f + __expf(-o3));
    *(float4*)(op + l0) = r;
}

__device__ __forceinline__ float softplusf(float x) {
    return (x > 20.f) ? x : log1pf(__expf(x));
}

// ---------------- delta = softplus(W_dt @ dt_low + b_dt) ----------------
__global__ __launch_bounds__(256) void delta_kernel(
    const float* __restrict__ xdbl,
    const float* __restrict__ Wdt0, const float* __restrict__ bdt0,
    const float* __restrict__ Wdt1, const float* __restrict__ bdt1,
    float* __restrict__ delta)
{
    const int gid = blockIdx.x * 256 + threadIdx.x;
    const int l4 = gid & (LL / 4 - 1);
    const int e = (gid >> 10) & (DI - 1);
    const int zi = gid >> 18;
    const float* Wdt = (zi >= BB) ? Wdt1 : Wdt0;
    const float* bdt = (zi >= BB) ? bdt1 : bdt0;
    const float bias = bdt[e];
    const float* xb = xdbl + (size_t)zi * DX * LL;
    const int l0 = l4 * 4;
    float a0 = bias, a1 = bias, a2 = bias, a3 = bias;
    #pragma unroll
    for (int r = 0; r < DR; r++) {
        const float w = Wdt[e * DR + r];
        const float4 v = *(const float4*)(xb + (size_t)r * LL + l0);
        a0 = fmaf(w, v.x, a0); a1 = fmaf(w, v.y, a1);
        a2 = fmaf(w, v.z, a2); a3 = fmaf(w, v.w, a3);
    }
    float4 r4;
    r4.x = softplusf(a0); r4.y = softplusf(a1);
    r4.z = softplusf(a2); r4.w = softplusf(a3);
    *(float4*)(delta + ((size_t)zi * DI + e) * LL + l0) = r4;
}

// ================= Chunked selective scan (coalesced) =================
__global__ __launch_bounds__(256) void scan_part1(
    const float* __restrict__ delta, const float* __restrict__ xc,
    const float* __restrict__ xdbl, const float* __restrict__ A_log,
    float* __restrict__ Ssum, float* __restrict__ sumdl)
{
    const int blk = blockIdx.x;          // zi*DI + d
    const int zi = blk >> 8;
    const int d  = blk & (DI - 1);
    const int t = threadIdx.x;
    __shared__ float s[2][LL];
    const float* dl_g = delta + (size_t)blk * LL;
    const float* x_g  = xc + (size_t)blk * LL;
    #pragma unroll
    for (int j = 0; j < 4; j++) {
        const int idx = (j * 256 + t) * 4;
        const float4 dv = *(const float4*)(dl_g + idx);
        const float4 xv = *(const float4*)(x_g + idx);
        const int c = idx >> 4;
        const int ib = idx & 15;
        s[0][SIDX(ib + 0, c)] = dv.x; s[0][SIDX(ib + 1, c)] = dv.y;
        s[0][SIDX(ib + 2, c)] = dv.z; s[0][SIDX(ib + 3, c)] = dv.w;
        s[1][SIDX(ib + 0, c)] = xv.x; s[1][SIDX(ib + 1, c)] = xv.y;
        s[1][SIDX(ib + 2, c)] = xv.z; s[1][SIDX(ib + 3, c)] = xv.w;
    }
    __syncthreads();
    float rdl[CH], rdlx[CH];
    float sdl = 0.f;
    #pragma unroll
    for (int i = 0; i < CH; i++) {
        rdl[i] = s[0][SIDX(i, t)];
        rdlx[i] = rdl[i] * s[1][SIDX(i, t)];
        sdl += rdl[i];
    }
    sumdl[(size_t)blk * NCH + t] = sdl;
    __syncthreads();
    const float* Bbase = xdbl + (size_t)zi * DX * LL + (size_t)DR * LL;
    #pragma unroll
    for (int j = 0; j < 4; j++) {
        const int idx = (j * 256 + t) * 4;
        const float4 bv = *(const float4*)(Bbase + idx);
        const int c = idx >> 4, ib = idx & 15;
        s[0][SIDX(ib + 0, c)] = bv.x; s[0][SIDX(ib + 1, c)] = bv.y;
        s[0][SIDX(ib + 2, c)] = bv.z; s[0][SIDX(ib + 3, c)] = bv.w;
    }
    __syncthreads();
    for (int n = 0; n < DS; n++) {
        if (n < DS - 1) {
            const float* Bn = Bbase + (size_t)(n + 1) * LL;
            float* dst = s[(n + 1) & 1];
            #pragma unroll
            for (int j = 0; j < 4; j++) {
                const int idx = (j * 256 + t) * 4;
                const float4 bv = *(const float4*)(Bn + idx);
                const int c = idx >> 4, ib = idx & 15;
                dst[SIDX(ib + 0, c)] = bv.x; dst[SIDX(ib + 1, c)] = bv.y;
                dst[SIDX(ib + 2, c)] = bv.z; dst[SIDX(ib + 3, c)] = bv.w;
            }
        }
        const float An = -__expf(A_log[d * DS + n]);
        const float* sb = s[n & 1];
        float hn = 0.f;
        #pragma unroll
        for (int i = 0; i < CH; i++) {
            hn = fmaf(__expf(rdl[i] * An), hn, rdlx[i] * sb[SIDX(i, t)]);
        }
        Ssum[((size_t)blk * DS + n) * NCH + t] = hn;
        __syncthreads();
    }
}

__global__ __launch_bounds__(256) void scan_part2(
    float* S, const float* __restrict__ sumdl, const float* __restrict__ A_log)
{
    const int tid = blockIdx.x * 256 + threadIdx.x;  // (zi*DI+d)*DS + n
    const int n = tid & (DS - 1);
    const int row = tid >> 4;
    const int d = row & (DI - 1);
    const float An = -__expf(A_log[d * DS + n]);
    const size_t base = (size_t)tid * NCH;
    const size_t dbase = (size_t)row * NCH;
    float h = 0.f;
    for (int c = 0; c < NCH; c++) {
        const float tmp = S[base + c];
        const float p = __expf(An * sumdl[dbase + c]);
        S[base + c] = h;
        h = fmaf(p, h, tmp);
    }
}

__global__ __launch_bounds__(256) void scan_part3(
    const float* __restrict__ delta, const float* __restrict__ xc,
    const float* __restrict__ xdbl, const float* __restrict__ A_log,
    const float* __restrict__ hin,
    const float* __restrict__ D0, const float* __restrict__ D1,
    float* __restrict__ zy)
{
    const int blk = blockIdx.x;
    const int zi = blk >> 8;
    const int d  = blk & (DI - 1);
    const int t = threadIdx.x;
    __shared__ float s[2][LL];
    const float* dl_g = delta + (size_t)blk * LL;
    const float* x_g  = xc + (size_t)blk * LL;
    float* zy_g = zy + (size_t)blk * LL;
    #pragma unroll
    for (int j = 0; j < 4; j++) {
        const int idx = (j * 256 + t) * 4;
        const float4 dv = *(const float4*)(dl_g + idx);
        const float4 xv = *(const float4*)(x_g + idx);
        const int c = idx >> 4, ib = idx & 15;
        s[0][SIDX(ib + 0, c)] = dv.x; s[0][SIDX(ib + 1, c)] = dv.y;
        s[0][SIDX(ib + 2, c)] = dv.z; s[0][SIDX(ib + 3, c)] = dv.w;
        s[1][SIDX(ib + 0, c)] = xv.x; s[1][SIDX(ib + 1, c)] = xv.y;
        s[1][SIDX(ib + 2, c)] = xv.z; s[1][SIDX(ib + 3, c)] = xv.w;
    }
    __syncthreads();
    float rdl[CH], rdlx[CH], y[CH];
    #pragma unroll
    for (int i = 0; i < CH; i++) {
        rdl[i] = s[0][SIDX(i, t)];
        rdlx[i] = rdl[i] * s[1][SIDX(i, t)];
        y[i] = 0.f;
    }
    __syncthreads();
    const float* Bbase = xdbl + (size_t)zi * DX * LL + (size_t)DR * LL;
    const float* Cbase = Bbase + (size_t)DS * LL;
    for (int n = 0; n < DS; n++) {
        #pragma unroll
        for (int j = 0; j < 4; j++) {
            const int idx = (j * 256 + t) * 4;
            const float4 bv = *(const float4*)(Bbase + (size_t)n * LL + idx);
            const float4 cv = *(const float4*)(Cbase + (size_t)n * LL + idx);
            const int c = idx >> 4, ib = idx & 15;
            s[0][SIDX(ib + 0, c)] = bv.x; s[0][SIDX(ib + 1, c)] = bv.y;
            s[0][SIDX(ib + 2, c)] = bv.z; s[0][SIDX(ib + 3, c)] = bv.w;
            s[1][SIDX(ib + 0, c)] = cv.x; s[1][SIDX(ib + 1, c)] = cv.y;
            s[1][SIDX(ib + 2, c)] = cv.z; s[1][SIDX(ib + 3, c)] = cv.w;
        }
        __syncthreads();
        const float An = -__expf(A_log[d * DS + n]);
        float hn = hin[((size_t)blk * DS + n) * NCH + t];
        #pragma unroll
        for (int i = 0; i < CH; i++) {
            hn = fmaf(__expf(rdl[i] * An), hn, rdlx[i] * s[0][SIDX(i, t)]);
            y[i] = fmaf(hn, s[1][SIDX(i, t)], y[i]);
        }
        __syncthreads();
    }
    #pragma unroll
    for (int i = 0; i < CH; i++) s[0][SIDX(i, t)] = y[i];
    const float Dd = ((zi >= BB) ? D1 : D0)[d];
    __syncthreads();
    #pragma unroll
    for (int j = 0; j < 4; j++) {
        const int idx = (j * 256 + t) * 4;
        const int c = idx >> 4, ib = idx & 15;
        const float4 zv = *(const float4*)(zy_g + idx);
        const float4 xv = *(const float4*)(x_g + idx);
        float4 r;
        r.x = (s[0][SIDX(ib + 0, c)] + Dd * xv.x) * (zv.x / (1.f + __expf(-zv.x)));
        r.y = (s[0][SIDX(ib + 1, c)] + Dd * xv.y) * (zv.y / (1.f + __expf(-zv.y)));
        r.z = (s[0][SIDX(ib + 2, c)] + Dd * xv.z) * (zv.z / (1.f + __expf(-zv.z)));
        r.w = (s[0][SIDX(ib + 3, c)] + Dd * xv.w) * (zv.w / (1.f + __expf(-zv.w)));
        *(float4*)(zy_g + idx) = r;
    }
}

extern "C" void kernel_launch(void* const* d_in, const int* in_sizes, int n_in,
                              void* d_out, int out_size, void* d_ws, size_t ws_size,
                              hipStream_t stream)
{
    (void)in_sizes; (void)n_in; (void)out_size; (void)ws_size;
    auto fp = [&](int i) { return (const float*)d_in[i]; };
    const float *pan = fp(0), *ms = fp(1);
    const float *nwp = fp(2), *nbp = fp(3), *nwm = fp(4), *nbm = fp(5);
    const float *Winp = fp(6), *Winm = fp(7), *Wzp = fp(8), *Wzm = fp(9);
    const float *cwp = fp(10), *cbp = fp(11), *cwm = fp(12), *cbm = fp(13);
    const float *Wxp = fp(14), *Wxm = fp(15);
    const float *Wdtp = fp(16), *Wdtm = fp(17), *bdtp = fp(18), *bdtm = fp(19);
    const float *Alog = fp(20), *Dp = fp(21), *Dm = fp(22);
    const float *Woutp = fp(23), *Woutm = fp(24);

    float* ws = (float*)d_ws;
    float* x3   = ws;                          // NZ*CC*LL
    float* xpre = x3 + (size_t)NZ * CC * LL;   // NZ*DI*LL (reused as delta)
    float* zy   = xpre + (size_t)NZ * DI * LL; // NZ*DI*LL (z, then y in place)
    float* xcv  = zy + (size_t)NZ * DI * LL;   // NZ*DI*LL (conv output)
    float* xdbl = xcv + (size_t)NZ * DI * LL;  // NZ*DX*LL
    float* Ssum = xdbl + (size_t)NZ * DX * LL; // NZ*DI*DS*NCH (in-place -> hin)
    float* sumdl = Ssum + (size_t)NZ * DI * DS * NCH; // NZ*DI*NCH
    unsigned short* wb = (unsigned short*)(sumdl + (size_t)NZ * DI * NCH); // 196608 bf16
    float* delta = xpre;
    float* out = (float*)d_out;

    convert_w_kernel<<<dim3(196608 / 256), 256, 0, stream>>>(Winp, Winm, Wzp, Wzm, Woutp, Woutm, wb);
    layernorm_kernel<<<dim3(LL / 64, NZ), 256, 0, stream>>>(pan, ms, nwp, nbp, nwm, nbm, x3);
    gemm_inz_mfma<<<dim3(LL / 64, 8, NZ), 256, 0, stream>>>(wb, x3, xpre, zy);
    conv_silu_kernel<<<dim3(NZ * DI * (LL / 4) / 256), 256, 0, stream>>>(xpre, cwp, cbp, cwm, cbm, xcv);
    gemm_kernel<<<dim3(LL / 64, 1, NZ), 256, 0, stream>>>(Wxp, Wxm, xcv, xdbl, DX, DI, LL);
    delta_kernel<<<dim3(NZ * DI * (LL / 4) / 256), 256, 0, stream>>>(xdbl, Wdtp, bdtp, Wdtm, bdtm, delta);
    scan_part1<<<dim3(NZ * DI), 256, 0, stream>>>(delta, xcv, xdbl, Alog, Ssum, sumdl);
    scan_part2<<<dim3(NZ * DI * DS / 256), 256, 0, stream>>>(Ssum, sumdl, Alog);
    scan_part3<<<dim3(NZ * DI), 256, 0, stream>>>(delta, xcv, xdbl, Alog, Ssum, Dp, Dm, zy);
    gemm_out_mfma<<<dim3(LL / 64, 2, NZ), 256, 0, stream>>>(wb, zy, out);
}

// Round 6
// 243.795 us; speedup vs baseline: 7.6897x; 1.0807x over previous
//
#include <hip/hip_runtime.h>
#include <hip/hip_bf16.h>

// Problem constants
constexpr int BB = 2;        // batch
constexpr int CC = 128;      // channels
constexpr int LL = 4096;     // H*W sequence length
constexpr int DI = 256;      // d_inner
constexpr int DS = 16;       // d_state
constexpr int DR = 8;        // dt_rank
constexpr int DX = 40;       // dt_rank + 2*d_state
constexpr int NZ = 2 * BB;   // branches * batch
constexpr int CH = 16;       // scan chunk length
constexpr int NCH = LL / CH; // 256 chunks == threads per scan WG

typedef short bf16x8 __attribute__((ext_vector_type(8)));
typedef float f32x4 __attribute__((ext_vector_type(4)));

__device__ __forceinline__ unsigned short f2bf(float x) {
    __hip_bfloat16 h = __float2bfloat16(x);
    return *(unsigned short*)&h;
}
__device__ __forceinline__ float siluf(float x) { return x / (1.f + __expf(-x)); }

// Chunk-transposed LDS index for the scan kernels.
__device__ __forceinline__ int SIDX(int i, int c) {
    return i * NCH + (c ^ (((i >> 2) & 3) << 3));
}

// ---------------- Weight fp32 -> bf16 conversion (once per call) -------------
// Offsets: Winp 0, Winm 32768, Wzp 65536, Wzm 98304, Woutp 131072,
//          Woutm 163840, Wxp 196608, Wxm 206848; total 217088 (= 848*256).
__global__ __launch_bounds__(256) void convert_w_kernel(
    const float* __restrict__ Winp, const float* __restrict__ Winm,
    const float* __restrict__ Wzp, const float* __restrict__ Wzm,
    const float* __restrict__ Woutp, const float* __restrict__ Woutm,
    const float* __restrict__ Wxp, const float* __restrict__ Wxm,
    unsigned short* __restrict__ dst)
{
    const int i = blockIdx.x * 256 + threadIdx.x;
    const float* src; int off;
    if (i < 32768)       { src = Winp;  off = i; }
    else if (i < 65536)  { src = Winm;  off = i - 32768; }
    else if (i < 98304)  { src = Wzp;   off = i - 65536; }
    else if (i < 131072) { src = Wzm;   off = i - 98304; }
    else if (i < 163840) { src = Woutp; off = i - 131072; }
    else if (i < 196608) { src = Woutm; off = i - 163840; }
    else if (i < 206848) { src = Wxp;   off = i - 196608; }
    else                 { src = Wxm;   off = i - 206848; }
    dst[i] = f2bf(src[off]);
}

// ---------------- LayerNorm over C -> bf16 x3, (zi, C, L) layout -------------
__global__ __launch_bounds__(256) void layernorm_kernel(
    const float* __restrict__ pan, const float* __restrict__ ms,
    const float* __restrict__ wpan, const float* __restrict__ bpan,
    const float* __restrict__ wms, const float* __restrict__ bms,
    unsigned short* __restrict__ x3b)
{
    const int zi = blockIdx.y;
    const int br = zi >> 1, b = zi & 1;
    const float* inp = br ? ms : pan;
    const float* wp = br ? wms : wpan;
    const float* bp = br ? bms : bpan;
    const int l0 = blockIdx.x * 64;
    const int t = threadIdx.x;
    const int lo = t & 63, c4 = t >> 6;
    const float* base = inp + (size_t)b * CC * LL + l0 + lo;
    float vals[32];
    float s = 0.f, s2 = 0.f;
    #pragma unroll
    for (int i = 0; i < 32; i++) {
        const int c = c4 * 32 + i;
        const float v = base[(size_t)c * LL];
        vals[i] = v; s += v; s2 += v * v;
    }
    __shared__ float red[2][4][64];
    red[0][c4][lo] = s; red[1][c4][lo] = s2;
    __syncthreads();
    const float S  = red[0][0][lo] + red[0][1][lo] + red[0][2][lo] + red[0][3][lo];
    const float S2 = red[1][0][lo] + red[1][1][lo] + red[1][2][lo] + red[1][3][lo];
    const float mu = S * (1.f / CC);
    const float var = S2 * (1.f / CC) - mu * mu;
    const float rstd = rsqrtf(var + 1e-5f);
    unsigned short* out = x3b + (size_t)zi * CC * LL + l0 + lo;
    #pragma unroll
    for (int i = 0; i < 32; i++) {
        const int c = c4 * 32 + i;
        out[(size_t)c * LL] = f2bf((vals[i] - mu) * rstd * wp[c] + bp[c]);
    }
}

// ================= MFMA bf16 GEMMs =================
// Tile 64M x 64N, 256 thr / 4 waves, K-chunks of 32 staged in LDS [64n][40k]
// (pair-packed; rows 80 B). A layout: m=lane&15, k=(lane>>4)*8+j.
// C/D: col(n)=lane&15, row(m)=(lane>>4)*4+reg.

// Fused W_in + W_z: my 0..3 -> W_in -> xpre; my 4..7 -> W_z -> zy. X = bf16 x3.
__global__ __launch_bounds__(256) void gemm_inz_mfma(
    const unsigned short* __restrict__ wb, const unsigned short* __restrict__ x3b,
    float* __restrict__ xpre, float* __restrict__ zy)
{
    const int zi = blockIdx.z;
    const int my = blockIdx.y;
    const unsigned short* W = wb + (my >= 4 ? 65536 : 0) + (zi >= BB ? 32768 : 0);
    float* outp = (my >= 4) ? zy : xpre;
    const int mbase = (my & 3) * 64;
    const unsigned short* Xb = x3b + (size_t)zi * CC * LL;
    const int n0 = blockIdx.x * 64;
    const int t = threadIdx.x;
    const int w = t >> 6, ln = t & 63;
    const int nf = ln & 15, qb = ln >> 4;
    bf16x8 afrag[4];
    const int mrow = mbase + w * 16 + nf;
    #pragma unroll
    for (int c = 0; c < 4; c++)
        afrag[c] = *(const bf16x8*)(W + (size_t)mrow * CC + c * 32 + qb * 8);
    __shared__ unsigned short Bs[64][40];
    unsigned* Bw = (unsigned*)Bs;
    f32x4 acc[4] = {};
    const int kp = t >> 4, n4 = (t & 15) * 4;
    #pragma unroll
    for (int kc = 0; kc < 4; kc++) {
        const ushort4 a0 = *(const ushort4*)(Xb + (size_t)(kc * 32 + 2 * kp) * LL + n0 + n4);
        const ushort4 a1 = *(const ushort4*)(Xb + (size_t)(kc * 32 + 2 * kp + 1) * LL + n0 + n4);
        if (kc) __syncthreads();
        Bw[(n4 + 0) * 20 + kp] = (unsigned)a0.x | ((unsigned)a1.x << 16);
        Bw[(n4 + 1) * 20 + kp] = (unsigned)a0.y | ((unsigned)a1.y << 16);
        Bw[(n4 + 2) * 20 + kp] = (unsigned)a0.z | ((unsigned)a1.z << 16);
        Bw[(n4 + 3) * 20 + kp] = (unsigned)a0.w | ((unsigned)a1.w << 16);
        __syncthreads();
        #pragma unroll
        for (int ns = 0; ns < 4; ns++) {
            const bf16x8 bf = *(const bf16x8*)(&Bs[ns * 16 + nf][qb * 8]);
            acc[ns] = __builtin_amdgcn_mfma_f32_16x16x32_bf16(afrag[kc], bf, acc[ns], 0, 0, 0);
        }
    }
    #pragma unroll
    for (int ns = 0; ns < 4; ns++)
        #pragma unroll
        for (int r = 0; r < 4; r++) {
            const int m = mbase + w * 16 + qb * 4 + r;
            outp[((size_t)zi * DI + m) * LL + n0 + ns * 16 + nf] = acc[ns][r];
        }
}

// W_x GEMM with fused causal-conv+SiLU staging: xdbl[zi,m,n] =
//   sum_e Wx[m,e] * silu(conv(xpre[zi,e,:]))[n].  M=40 in a 64-row tile.
__global__ __launch_bounds__(256) void gemm_x_mfma(
    const unsigned short* __restrict__ wb, const float* __restrict__ xpre,
    const float* __restrict__ cw0, const float* __restrict__ cb0,
    const float* __restrict__ cw1, const float* __restrict__ cb1,
    float* __restrict__ xdbl)
{
    const int zi = blockIdx.z;
    const unsigned short* W = wb + 196608 + (zi >= BB ? 10240 : 0);
    const float* cw = (zi >= BB) ? cw1 : cw0;
    const float* cb = (zi >= BB) ? cb1 : cb0;
    const float* Xb = xpre + (size_t)zi * DI * LL;
    const int n0 = blockIdx.x * 64;
    const int t = threadIdx.x;
    const int w = t >> 6, ln = t & 63;
    const int nf = ln & 15, qb = ln >> 4;
    bf16x8 zfrag;
    #pragma unroll
    for (int j = 0; j < 8; j++) zfrag[j] = 0;
    bf16x8 afrag[8];
    const int mrow = w * 16 + nf;
    #pragma unroll
    for (int c = 0; c < 8; c++)
        afrag[c] = (mrow < DX) ? *(const bf16x8*)(W + (size_t)mrow * DI + c * 32 + qb * 8) : zfrag;
    __shared__ unsigned short Bs[64][40];
    unsigned* Bw = (unsigned*)Bs;
    f32x4 acc[4] = {};
    const int kp = t >> 4, n4 = (t & 15) * 4;
    #pragma unroll
    for (int kc = 0; kc < 8; kc++) {
        float vals[2][4];
        #pragma unroll
        for (int rr = 0; rr < 2; rr++) {
            const int e = kc * 32 + 2 * kp + rr;
            const float* xp = Xb + (size_t)e * LL + n0 + n4;
            const float4 cur = *(const float4*)xp;
            float xm1, xm2, xm3;
            if (n0 + n4 == 0) { xm1 = 0.f; xm2 = 0.f; xm3 = 0.f; }
            else { xm1 = xp[-1]; xm2 = xp[-2]; xm3 = xp[-3]; }
            const float w0 = cw[e * 4 + 0], w1 = cw[e * 4 + 1];
            const float w2 = cw[e * 4 + 2], w3 = cw[e * 4 + 3];
            const float bias = cb[e];
            vals[rr][0] = siluf(w0 * xm3 + w1 * xm2 + w2 * xm1 + w3 * cur.x + bias);
            vals[rr][1] = siluf(w0 * xm2 + w1 * xm1 + w2 * cur.x + w3 * cur.y + bias);
            vals[rr][2] = siluf(w0 * xm1 + w1 * cur.x + w2 * cur.y + w3 * cur.z + bias);
            vals[rr][3] = siluf(w0 * cur.x + w1 * cur.y + w2 * cur.z + w3 * cur.w + bias);
        }
        if (kc) __syncthreads();
        #pragma unroll
        for (int j = 0; j < 4; j++)
            Bw[(n4 + j) * 20 + kp] = (unsigned)f2bf(vals[0][j]) | ((unsigned)f2bf(vals[1][j]) << 16);
        __syncthreads();
        #pragma unroll
        for (int ns = 0; ns < 4; ns++) {
            const bf16x8 bf = *(const bf16x8*)(&Bs[ns * 16 + nf][qb * 8]);
            acc[ns] = __builtin_amdgcn_mfma_f32_16x16x32_bf16(afrag[kc], bf, acc[ns], 0, 0, 0);
        }
    }
    #pragma unroll
    for (int ns = 0; ns < 4; ns++)
        #pragma unroll
        for (int r = 0; r < 4; r++) {
            const int m = w * 16 + qb * 4 + r;
            if (m < DX)
                xdbl[((size_t)zi * DX + m) * LL + n0 + ns * 16 + nf] = acc[ns][r];
        }
}

// W_out: M=128, K=256, writes d_out fp32 at (zi*CC + m)*LL + n
__global__ __launch_bounds__(256) void gemm_out_mfma(
    const unsigned short* __restrict__ wb, const float* __restrict__ y,
    float* __restrict__ outg)
{
    const int zi = blockIdx.z;
    const unsigned short* W = wb + 131072 + (zi >= BB ? 32768 : 0);
    const int mbase = blockIdx.y * 64;
    const float* Xb = y + (size_t)zi * DI * LL;
    const int n0 = blockIdx.x * 64;
    const int t = threadIdx.x;
    const int w = t >> 6, ln = t & 63;
    const int nf = ln & 15, qb = ln >> 4;
    bf16x8 afrag[8];
    const int mrow = mbase + w * 16 + nf;
    #pragma unroll
    for (int c = 0; c < 8; c++)
        afrag[c] = *(const bf16x8*)(W + (size_t)mrow * DI + c * 32 + qb * 8);
    __shared__ unsigned short Bs[64][40];
    unsigned* Bw = (unsigned*)Bs;
    f32x4 acc[4] = {};
    const int kp = t >> 4, n4 = (t & 15) * 4;
    #pragma unroll
    for (int kc = 0; kc < 8; kc++) {
        const float* src = Xb + (size_t)(kc * 32 + 2 * kp) * LL + n0 + n4;
        const float4 r0 = *(const float4*)src;
        const float4 r1 = *(const float4*)(src + LL);
        if (kc) __syncthreads();
        Bw[(n4 + 0) * 20 + kp] = (unsigned)f2bf(r0.x) | ((unsigned)f2bf(r1.x) << 16);
        Bw[(n4 + 1) * 20 + kp] = (unsigned)f2bf(r0.y) | ((unsigned)f2bf(r1.y) << 16);
        Bw[(n4 + 2) * 20 + kp] = (unsigned)f2bf(r0.z) | ((unsigned)f2bf(r1.z) << 16);
        Bw[(n4 + 3) * 20 + kp] = (unsigned)f2bf(r0.w) | ((unsigned)f2bf(r1.w) << 16);
        __syncthreads();
        #pragma unroll
        for (int ns = 0; ns < 4; ns++) {
            const bf16x8 bf = *(const bf16x8*)(&Bs[ns * 16 + nf][qb * 8]);
            acc[ns] = __builtin_amdgcn_mfma_f32_16x16x32_bf16(afrag[kc], bf, acc[ns], 0, 0, 0);
        }
    }
    #pragma unroll
    for (int ns = 0; ns < 4; ns++)
        #pragma unroll
        for (int r = 0; r < 4; r++) {
            const int m = mbase + w * 16 + qb * 4 + r;
            outg[((size_t)zi * CC + m) * LL + n0 + ns * 16 + nf] = acc[ns][r];
        }
}

__device__ __forceinline__ float softplusf(float x) {
    return (x > 20.f) ? x : log1pf(__expf(x));
}

// ---------------- delta = softplus(W_dt @ dt_low + b_dt) ----------------
__global__ __launch_bounds__(256) void delta_kernel(
    const float* __restrict__ xdbl,
    const float* __restrict__ Wdt0, const float* __restrict__ bdt0,
    const float* __restrict__ Wdt1, const float* __restrict__ bdt1,
    float* __restrict__ delta)
{
    const int gid = blockIdx.x * 256 + threadIdx.x;
    const int l4 = gid & (LL / 4 - 1);
    const int e = (gid >> 10) & (DI - 1);
    const int zi = gid >> 18;
    const float* Wdt = (zi >= BB) ? Wdt1 : Wdt0;
    const float* bdt = (zi >= BB) ? bdt1 : bdt0;
    const float bias = bdt[e];
    const float* xb = xdbl + (size_t)zi * DX * LL;
    const int l0 = l4 * 4;
    float a0 = bias, a1 = bias, a2 = bias, a3 = bias;
    #pragma unroll
    for (int r = 0; r < DR; r++) {
        const float w = Wdt[e * DR + r];
        const float4 v = *(const float4*)(xb + (size_t)r * LL + l0);
        a0 = fmaf(w, v.x, a0); a1 = fmaf(w, v.y, a1);
        a2 = fmaf(w, v.z, a2); a3 = fmaf(w, v.w, a3);
    }
    float4 r4;
    r4.x = softplusf(a0); r4.y = softplusf(a1);
    r4.z = softplusf(a2); r4.w = softplusf(a3);
    *(float4*)(delta + ((size_t)zi * DI + e) * LL + l0) = r4;
}

// ================= Chunked selective scan (conv fused in staging) ============
// WG = one (zi,d) row; thread t = chunk t.  x = silu(conv(xpre)) computed
// in-register from the LDS-staged raw xpre row (halo from chunk t-1).

__global__ __launch_bounds__(256) void scan_part1(
    const float* __restrict__ delta, const float* __restrict__ xpre,
    const float* __restrict__ xdbl, const float* __restrict__ A_log,
    const float* __restrict__ cw0, const float* __restrict__ cb0,
    const float* __restrict__ cw1, const float* __restrict__ cb1,
    float* __restrict__ Ssum, float* __restrict__ sumdl)
{
    const int blk = blockIdx.x;          // zi*DI + d
    const int zi = blk >> 8;
    const int d  = blk & (DI - 1);
    const int t = threadIdx.x;
    __shared__ float s[2][LL];
    const float* dl_g = delta + (size_t)blk * LL;
    const float* x_g  = xpre + (size_t)blk * LL;
    #pragma unroll
    for (int j = 0; j < 4; j++) {
        const int idx = (j * 256 + t) * 4;
        const float4 dv = *(const float4*)(dl_g + idx);
        const float4 xv = *(const float4*)(x_g + idx);
        const int c = idx >> 4, ib = idx & 15;
        s[0][SIDX(ib + 0, c)] = dv.x; s[0][SIDX(ib + 1, c)] = dv.y;
        s[0][SIDX(ib + 2, c)] = dv.z; s[0][SIDX(ib + 3, c)] = dv.w;
        s[1][SIDX(ib + 0, c)] = xv.x; s[1][SIDX(ib + 1, c)] = xv.y;
        s[1][SIDX(ib + 2, c)] = xv.z; s[1][SIDX(ib + 3, c)] = xv.w;
    }
    __syncthreads();
    const float* cw = (zi >= BB) ? cw1 : cw0;
    const float* cb = (zi >= BB) ? cb1 : cb0;
    const float w0 = cw[d * 4 + 0], w1 = cw[d * 4 + 1];
    const float w2 = cw[d * 4 + 2], w3 = cw[d * 4 + 3];
    const float cbias = cb[d];
    float xw[CH + 3];
    const int tm1 = (t > 0) ? t - 1 : 0;
    #pragma unroll
    for (int j = 0; j < 3; j++) {
        const float v = s[1][SIDX(13 + j, tm1)];
        xw[j] = (t > 0) ? v : 0.f;
    }
    #pragma unroll
    for (int i = 0; i < CH; i++) xw[i + 3] = s[1][SIDX(i, t)];
    float rdl[CH], rdlx[CH];
    float sdl = 0.f;
    #pragma unroll
    for (int i = 0; i < CH; i++) {
        rdl[i] = s[0][SIDX(i, t)];
        sdl += rdl[i];
        const float rx = siluf(w0 * xw[i] + w1 * xw[i + 1] + w2 * xw[i + 2] + w3 * xw[i + 3] + cbias);
        rdlx[i] = rdl[i] * rx;
    }
    sumdl[(size_t)blk * NCH + t] = sdl;
    __syncthreads();
    const float* Bbase = xdbl + (size_t)zi * DX * LL + (size_t)DR * LL;
    #pragma unroll
    for (int j = 0; j < 4; j++) {
        const int idx = (j * 256 + t) * 4;
        const float4 bv = *(const float4*)(Bbase + idx);
        const int c = idx >> 4, ib = idx & 15;
        s[0][SIDX(ib + 0, c)] = bv.x; s[0][SIDX(ib + 1, c)] = bv.y;
        s[0][SIDX(ib + 2, c)] = bv.z; s[0][SIDX(ib + 3, c)] = bv.w;
    }
    __syncthreads();
    for (int n = 0; n < DS; n++) {
        if (n < DS - 1) {
            const float* Bn = Bbase + (size_t)(n + 1) * LL;
            float* dst = s[(n + 1) & 1];
            #pragma unroll
            for (int j = 0; j < 4; j++) {
                const int idx = (j * 256 + t) * 4;
                const float4 bv = *(const float4*)(Bn + idx);
                const int c = idx >> 4, ib = idx & 15;
                dst[SIDX(ib + 0, c)] = bv.x; dst[SIDX(ib + 1, c)] = bv.y;
                dst[SIDX(ib + 2, c)] = bv.z; dst[SIDX(ib + 3, c)] = bv.w;
            }
        }
        const float An = -__expf(A_log[d * DS + n]);
        const float* sb = s[n & 1];
        float hn = 0.f;
        #pragma unroll
        for (int i = 0; i < CH; i++) {
            hn = fmaf(__expf(rdl[i] * An), hn, rdlx[i] * sb[SIDX(i, t)]);
        }
        Ssum[((size_t)blk * DS + n) * NCH + t] = hn;
        __syncthreads();
    }
}

__global__ __launch_bounds__(256) void scan_part2(
    float* S, const float* __restrict__ sumdl, const float* __restrict__ A_log)
{
    const int tid = blockIdx.x * 256 + threadIdx.x;  // (zi*DI+d)*DS + n
    const int n = tid & (DS - 1);
    const int row = tid >> 4;
    const int d = row & (DI - 1);
    const float An = -__expf(A_log[d * DS + n]);
    const size_t base = (size_t)tid * NCH;
    const size_t dbase = (size_t)row * NCH;
    float h = 0.f;
    #pragma unroll 4
    for (int c = 0; c < NCH; c++) {
        const float tmp = S[base + c];
        const float p = __expf(An * sumdl[dbase + c]);
        S[base + c] = h;
        h = fmaf(p, h, tmp);
    }
}

__global__ __launch_bounds__(256) void scan_part3(
    const float* __restrict__ delta, const float* __restrict__ xpre,
    const float* __restrict__ xdbl, const float* __restrict__ A_log,
    const float* __restrict__ hin,
    const float* __restrict__ cw0, const float* __restrict__ cb0,
    const float* __restrict__ cw1, const float* __restrict__ cb1,
    const float* __restrict__ D0, const float* __restrict__ D1,
    float* __restrict__ zy)
{
    const int blk = blockIdx.x;
    const int zi = blk >> 8;
    const int d  = blk & (DI - 1);
    const int t = threadIdx.x;
    __shared__ float s[2][LL];
    const float* dl_g = delta + (size_t)blk * LL;
    const float* x_g  = xpre + (size_t)blk * LL;
    float* zy_g = zy + (size_t)blk * LL;
    #pragma unroll
    for (int j = 0; j < 4; j++) {
        const int idx = (j * 256 + t) * 4;
        const float4 dv = *(const float4*)(dl_g + idx);
        const float4 xv = *(const float4*)(x_g + idx);
        const int c = idx >> 4, ib = idx & 15;
        s[0][SIDX(ib + 0, c)] = dv.x; s[0][SIDX(ib + 1, c)] = dv.y;
        s[0][SIDX(ib + 2, c)] = dv.z; s[0][SIDX(ib + 3, c)] = dv.w;
        s[1][SIDX(ib + 0, c)] = xv.x; s[1][SIDX(ib + 1, c)] = xv.y;
        s[1][SIDX(ib + 2, c)] = xv.z; s[1][SIDX(ib + 3, c)] = xv.w;
    }
    __syncthreads();
    const float* cw = (zi >= BB) ? cw1 : cw0;
    const float* cb = (zi >= BB) ? cb1 : cb0;
    const float w0 = cw[d * 4 + 0], w1 = cw[d * 4 + 1];
    const float w2 = cw[d * 4 + 2], w3 = cw[d * 4 + 3];
    const float cbias = cb[d];
    float xw[CH + 3];
    const int tm1 = (t > 0) ? t - 1 : 0;
    #pragma unroll
    for (int j = 0; j < 3; j++) {
        const float v = s[1][SIDX(13 + j, tm1)];
        xw[j] = (t > 0) ? v : 0.f;
    }
    #pragma unroll
    for (int i = 0; i < CH; i++) xw[i + 3] = s[1][SIDX(i, t)];
    float rdl[CH], rdlx[CH], rx[CH], y[CH];
    #pragma unroll
    for (int i = 0; i < CH; i++) {
        rdl[i] = s[0][SIDX(i, t)];
        rx[i] = siluf(w0 * xw[i] + w1 * xw[i + 1] + w2 * xw[i + 2] + w3 * xw[i + 3] + cbias);
        rdlx[i] = rdl[i] * rx[i];
        y[i] = 0.f;
    }
    __syncthreads();
    const float* Bbase = xdbl + (size_t)zi * DX * LL + (size_t)DR * LL;
    const float* Cbase = Bbase + (size_t)DS * LL;
    for (int n = 0; n < DS; n++) {
        #pragma unroll
        for (int j = 0; j < 4; j++) {
            const int idx = (j * 256 + t) * 4;
            const float4 bv = *(const float4*)(Bbase + (size_t)n * LL + idx);
            const float4 cv = *(const float4*)(Cbase + (size_t)n * LL + idx);
            const int c = idx >> 4, ib = idx & 15;
            s[0][SIDX(ib + 0, c)] = bv.x; s[0][SIDX(ib + 1, c)] = bv.y;
            s[0][SIDX(ib + 2, c)] = bv.z; s[0][SIDX(ib + 3, c)] = bv.w;
            s[1][SIDX(ib + 0, c)] = cv.x; s[1][SIDX(ib + 1, c)] = cv.y;
            s[1][SIDX(ib + 2, c)] = cv.z; s[1][SIDX(ib + 3, c)] = cv.w;
        }
        __syncthreads();
        const float An = -__expf(A_log[d * DS + n]);
        float hn = hin[((size_t)blk * DS + n) * NCH + t];
        #pragma unroll
        for (int i = 0; i < CH; i++) {
            hn = fmaf(__expf(rdl[i] * An), hn, rdlx[i] * s[0][SIDX(i, t)]);
            y[i] = fmaf(hn, s[1][SIDX(i, t)], y[i]);
        }
        __syncthreads();
    }
    // stash y and x (chunk-transposed), then cooperative gated write-out
    #pragma unroll
    for (int i = 0; i < CH; i++) {
        s[0][SIDX(i, t)] = y[i];
        s[1][SIDX(i, t)] = rx[i];
    }
    const float Dd = ((zi >= BB) ? D1 : D0)[d];
    __syncthreads();
    #pragma unroll
    for (int j = 0; j < 4; j++) {
        const int idx = (j * 256 + t) * 4;
        const int c = idx >> 4, ib = idx & 15;
        const float4 zv = *(const float4*)(zy_g + idx);
        float4 r;
        r.x = (s[0][SIDX(ib + 0, c)] + Dd * s[1][SIDX(ib + 0, c)]) * siluf(zv.x);
        r.y = (s[0][SIDX(ib + 1, c)] + Dd * s[1][SIDX(ib + 1, c)]) * siluf(zv.y);
        r.z = (s[0][SIDX(ib + 2, c)] + Dd * s[1][SIDX(ib + 2, c)]) * siluf(zv.z);
        r.w = (s[0][SIDX(ib + 3, c)] + Dd * s[1][SIDX(ib + 3, c)]) * siluf(zv.w);
        *(float4*)(zy_g + idx) = r;
    }
}

extern "C" void kernel_launch(void* const* d_in, const int* in_sizes, int n_in,
                              void* d_out, int out_size, void* d_ws, size_t ws_size,
                              hipStream_t stream)
{
    (void)in_sizes; (void)n_in; (void)out_size; (void)ws_size;
    auto fp = [&](int i) { return (const float*)d_in[i]; };
    const float *pan = fp(0), *ms = fp(1);
    const float *nwp = fp(2), *nbp = fp(3), *nwm = fp(4), *nbm = fp(5);
    const float *Winp = fp(6), *Winm = fp(7), *Wzp = fp(8), *Wzm = fp(9);
    const float *cwp = fp(10), *cbp = fp(11), *cwm = fp(12), *cbm = fp(13);
    const float *Wxp = fp(14), *Wxm = fp(15);
    const float *Wdtp = fp(16), *Wdtm = fp(17), *bdtp = fp(18), *bdtm = fp(19);
    const float *Alog = fp(20), *Dp = fp(21), *Dm = fp(22);
    const float *Woutp = fp(23), *Woutm = fp(24);

    float* ws = (float*)d_ws;
    unsigned short* x3b = (unsigned short*)ws;            // NZ*CC*LL bf16 = 1,048,576 float-slots
    float* xpre = ws + (size_t)NZ * CC * LL / 2;          // NZ*DI*LL f32 (live through part3)
    float* zy   = xpre + (size_t)NZ * DI * LL;            // NZ*DI*LL (z, then y in place)
    float* delta = zy + (size_t)NZ * DI * LL;             // NZ*DI*LL
    float* xdbl = delta + (size_t)NZ * DI * LL;           // NZ*DX*LL
    float* Ssum = xdbl + (size_t)NZ * DX * LL;            // NZ*DI*DS*NCH (in-place -> hin)
    float* sumdl = Ssum + (size_t)NZ * DI * DS * NCH;     // NZ*DI*NCH
    unsigned short* wb = (unsigned short*)(sumdl + (size_t)NZ * DI * NCH); // 217088 bf16
    float* out = (float*)d_out;

    convert_w_kernel<<<dim3(848), 256, 0, stream>>>(Winp, Winm, Wzp, Wzm, Woutp, Woutm, Wxp, Wxm, wb);
    layernorm_kernel<<<dim3(LL / 64, NZ), 256, 0, stream>>>(pan, ms, nwp, nbp, nwm, nbm, x3b);
    gemm_inz_mfma<<<dim3(LL / 64, 8, NZ), 256, 0, stream>>>(wb, x3b, xpre, zy);
    gemm_x_mfma<<<dim3(LL / 64, 1, NZ), 256, 0, stream>>>(wb, xpre, cwp, cbp, cwm, cbm, xdbl);
    delta_kernel<<<dim3(NZ * DI * (LL / 4) / 256), 256, 0, stream>>>(xdbl, Wdtp, bdtp, Wdtm, bdtm, delta);
    scan_part1<<<dim3(NZ * DI), 256, 0, stream>>>(delta, xpre, xdbl, Alog, cwp, cbp, cwm, cbm, Ssum, sumdl);
    scan_part2<<<dim3(NZ * DI * DS / 256), 256, 0, stream>>>(Ssum, sumdl, Alog);
    scan_part3<<<dim3(NZ * DI), 256, 0, stream>>>(delta, xpre, xdbl, Alog, Ssum, cwp, cbp, cwm, cbm, Dp, Dm, zy);
    gemm_out_mfma<<<dim3(LL / 64, 2, NZ), 256, 0, stream>>>(wb, zy, out);
}

// Round 8
// 230.151 us; speedup vs baseline: 8.1456x; 1.0593x over previous
//
#include <hip/hip_runtime.h>
#include <hip/hip_bf16.h>

// Problem constants
constexpr int BB = 2;        // batch
constexpr int CC = 128;      // channels
constexpr int LL = 4096;     // H*W sequence length
constexpr int DI = 256;      // d_inner
constexpr int DS = 16;       // d_state
constexpr int DR = 8;        // dt_rank
constexpr int DX = 40;       // dt_rank + 2*d_state
constexpr int NZ = 2 * BB;   // branches * batch
constexpr int CH = 16;       // scan chunk length
constexpr int NCH = LL / CH; // 256 chunks == threads per scan WG

typedef short bf16x8 __attribute__((ext_vector_type(8)));
typedef float f32x4 __attribute__((ext_vector_type(4)));

__device__ __forceinline__ unsigned short f2bf(float x) {
    __hip_bfloat16 h = __float2bfloat16(x);
    return *(unsigned short*)&h;
}
__device__ __forceinline__ float siluf(float x) { return x / (1.f + __expf(-x)); }
__device__ __forceinline__ float softplusf(float x) {
    return (x > 20.f) ? x : log1pf(__expf(x));
}

// Chunk-transposed LDS index for the scan kernel.
__device__ __forceinline__ int SIDX(int i, int c) {
    return i * NCH + (c ^ (((i >> 2) & 3) << 3));
}

// ---------------- Weight fp32 -> bf16 conversion (once per call) -------------
// Offsets: Winp 0, Winm 32768, Wzp 65536, Wzm 98304, Woutp 131072,
//          Woutm 163840, Wxp 196608, Wxm 206848; total 217088 (= 848*256).
__global__ __launch_bounds__(256) void convert_w_kernel(
    const float* __restrict__ Winp, const float* __restrict__ Winm,
    const float* __restrict__ Wzp, const float* __restrict__ Wzm,
    const float* __restrict__ Woutp, const float* __restrict__ Woutm,
    const float* __restrict__ Wxp, const float* __restrict__ Wxm,
    unsigned short* __restrict__ dst)
{
    const int i = blockIdx.x * 256 + threadIdx.x;
    const float* src; int off;
    if (i < 32768)       { src = Winp;  off = i; }
    else if (i < 65536)  { src = Winm;  off = i - 32768; }
    else if (i < 98304)  { src = Wzp;   off = i - 65536; }
    else if (i < 131072) { src = Wzm;   off = i - 98304; }
    else if (i < 163840) { src = Woutp; off = i - 131072; }
    else if (i < 196608) { src = Woutm; off = i - 163840; }
    else if (i < 206848) { src = Wxp;   off = i - 196608; }
    else                 { src = Wxm;   off = i - 206848; }
    dst[i] = f2bf(src[off]);
}

// ---------------- LayerNorm over C -> bf16 x3, (zi, C, L) layout -------------
__global__ __launch_bounds__(256) void layernorm_kernel(
    const float* __restrict__ pan, const float* __restrict__ ms,
    const float* __restrict__ wpan, const float* __restrict__ bpan,
    const float* __restrict__ wms, const float* __restrict__ bms,
    unsigned short* __restrict__ x3b)
{
    const int zi = blockIdx.y;
    const int br = zi >> 1, b = zi & 1;
    const float* inp = br ? ms : pan;
    const float* wp = br ? wms : wpan;
    const float* bp = br ? bms : bpan;
    const int l0 = blockIdx.x * 64;
    const int t = threadIdx.x;
    const int lo = t & 63, c4 = t >> 6;
    const float* base = inp + (size_t)b * CC * LL + l0 + lo;
    float vals[32];
    float s = 0.f, s2 = 0.f;
    #pragma unroll
    for (int i = 0; i < 32; i++) {
        const int c = c4 * 32 + i;
        const float v = base[(size_t)c * LL];
        vals[i] = v; s += v; s2 += v * v;
    }
    __shared__ float red[2][4][64];
    red[0][c4][lo] = s; red[1][c4][lo] = s2;
    __syncthreads();
    const float S  = red[0][0][lo] + red[0][1][lo] + red[0][2][lo] + red[0][3][lo];
    const float S2 = red[1][0][lo] + red[1][1][lo] + red[1][2][lo] + red[1][3][lo];
    const float mu = S * (1.f / CC);
    const float var = S2 * (1.f / CC) - mu * mu;
    const float rstd = rsqrtf(var + 1e-5f);
    unsigned short* out = x3b + (size_t)zi * CC * LL + l0 + lo;
    #pragma unroll
    for (int i = 0; i < 32; i++) {
        const int c = c4 * 32 + i;
        out[(size_t)c * LL] = f2bf((vals[i] - mu) * rstd * wp[c] + bp[c]);
    }
}

// ================= MFMA bf16 GEMMs =================
// Tile 64M x 64N, 256 thr / 4 waves, K-chunks of 32 staged in LDS [64n][40k].
// A layout: m=lane&15, k=(lane>>4)*8+j.  C/D: col(n)=lane&15, row(m)=(lane>>4)*4+reg.

// Fused W_in + W_z: my 0..3 -> W_in -> xpre; my 4..7 -> W_z -> zy. X = bf16 x3.
__global__ __launch_bounds__(256) void gemm_inz_mfma(
    const unsigned short* __restrict__ wb, const unsigned short* __restrict__ x3b,
    float* __restrict__ xpre, float* __restrict__ zy)
{
    const int zi = blockIdx.z;
    const int my = blockIdx.y;
    const unsigned short* W = wb + (my >= 4 ? 65536 : 0) + (zi >= BB ? 32768 : 0);
    float* outp = (my >= 4) ? zy : xpre;
    const int mbase = (my & 3) * 64;
    const unsigned short* Xb = x3b + (size_t)zi * CC * LL;
    const int n0 = blockIdx.x * 64;
    const int t = threadIdx.x;
    const int w = t >> 6, ln = t & 63;
    const int nf = ln & 15, qb = ln >> 4;
    bf16x8 afrag[4];
    const int mrow = mbase + w * 16 + nf;
    #pragma unroll
    for (int c = 0; c < 4; c++)
        afrag[c] = *(const bf16x8*)(W + (size_t)mrow * CC + c * 32 + qb * 8);
    __shared__ unsigned short Bs[64][40];
    unsigned* Bw = (unsigned*)Bs;
    f32x4 acc[4] = {};
    const int kp = t >> 4, n4 = (t & 15) * 4;
    #pragma unroll
    for (int kc = 0; kc < 4; kc++) {
        const ushort4 a0 = *(const ushort4*)(Xb + (size_t)(kc * 32 + 2 * kp) * LL + n0 + n4);
        const ushort4 a1 = *(const ushort4*)(Xb + (size_t)(kc * 32 + 2 * kp + 1) * LL + n0 + n4);
        if (kc) __syncthreads();
        Bw[(n4 + 0) * 20 + kp] = (unsigned)a0.x | ((unsigned)a1.x << 16);
        Bw[(n4 + 1) * 20 + kp] = (unsigned)a0.y | ((unsigned)a1.y << 16);
        Bw[(n4 + 2) * 20 + kp] = (unsigned)a0.z | ((unsigned)a1.z << 16);
        Bw[(n4 + 3) * 20 + kp] = (unsigned)a0.w | ((unsigned)a1.w << 16);
        __syncthreads();
        #pragma unroll
        for (int ns = 0; ns < 4; ns++) {
            const bf16x8 bf = *(const bf16x8*)(&Bs[ns * 16 + nf][qb * 8]);
            acc[ns] = __builtin_amdgcn_mfma_f32_16x16x32_bf16(afrag[kc], bf, acc[ns], 0, 0, 0);
        }
    }
    #pragma unroll
    for (int ns = 0; ns < 4; ns++)
        #pragma unroll
        for (int r = 0; r < 4; r++) {
            const int m = mbase + w * 16 + qb * 4 + r;
            outp[((size_t)zi * DI + m) * LL + n0 + ns * 16 + nf] = acc[ns][r];
        }
}

// W_x GEMM with fused causal-conv+SiLU staging: xdbl[zi,m,n] =
//   sum_e Wx[m,e] * silu(conv(xpre[zi,e,:]))[n].  M=40 in a 64-row tile.
__global__ __launch_bounds__(256) void gemm_x_mfma(
    const unsigned short* __restrict__ wb, const float* __restrict__ xpre,
    const float* __restrict__ cw0, const float* __restrict__ cb0,
    const float* __restrict__ cw1, const float* __restrict__ cb1,
    float* __restrict__ xdbl)
{
    const int zi = blockIdx.z;
    const unsigned short* W = wb + 196608 + (zi >= BB ? 10240 : 0);
    const float* cw = (zi >= BB) ? cw1 : cw0;
    const float* cb = (zi >= BB) ? cb1 : cb0;
    const float* Xb = xpre + (size_t)zi * DI * LL;
    const int n0 = blockIdx.x * 64;
    const int t = threadIdx.x;
    const int w = t >> 6, ln = t & 63;
    const int nf = ln & 15, qb = ln >> 4;
    bf16x8 zfrag;
    #pragma unroll
    for (int j = 0; j < 8; j++) zfrag[j] = 0;
    bf16x8 afrag[8];
    const int mrow = w * 16 + nf;
    #pragma unroll
    for (int c = 0; c < 8; c++)
        afrag[c] = (mrow < DX) ? *(const bf16x8*)(W + (size_t)mrow * DI + c * 32 + qb * 8) : zfrag;
    __shared__ unsigned short Bs[64][40];
    unsigned* Bw = (unsigned*)Bs;
    f32x4 acc[4] = {};
    const int kp = t >> 4, n4 = (t & 15) * 4;
    #pragma unroll
    for (int kc = 0; kc < 8; kc++) {
        float vals[2][4];
        #pragma unroll
        for (int rr = 0; rr < 2; rr++) {
            const int e = kc * 32 + 2 * kp + rr;
            const float* xp = Xb + (size_t)e * LL + n0 + n4;
            const float4 cur = *(const float4*)xp;
            float xm1, xm2, xm3;
            if (n0 + n4 == 0) { xm1 = 0.f; xm2 = 0.f; xm3 = 0.f; }
            else { xm1 = xp[-1]; xm2 = xp[-2]; xm3 = xp[-3]; }
            const float w0 = cw[e * 4 + 0], w1 = cw[e * 4 + 1];
            const float w2 = cw[e * 4 + 2], w3 = cw[e * 4 + 3];
            const float bias = cb[e];
            vals[rr][0] = siluf(w0 * xm3 + w1 * xm2 + w2 * xm1 + w3 * cur.x + bias);
            vals[rr][1] = siluf(w0 * xm2 + w1 * xm1 + w2 * cur.x + w3 * cur.y + bias);
            vals[rr][2] = siluf(w0 * xm1 + w1 * cur.x + w2 * cur.y + w3 * cur.z + bias);
            vals[rr][3] = siluf(w0 * cur.x + w1 * cur.y + w2 * cur.z + w3 * cur.w + bias);
        }
        if (kc) __syncthreads();
        #pragma unroll
        for (int j = 0; j < 4; j++)
            Bw[(n4 + j) * 20 + kp] = (unsigned)f2bf(vals[0][j]) | ((unsigned)f2bf(vals[1][j]) << 16);
        __syncthreads();
        #pragma unroll
        for (int ns = 0; ns < 4; ns++) {
            const bf16x8 bf = *(const bf16x8*)(&Bs[ns * 16 + nf][qb * 8]);
            acc[ns] = __builtin_amdgcn_mfma_f32_16x16x32_bf16(afrag[kc], bf, acc[ns], 0, 0, 0);
        }
    }
    #pragma unroll
    for (int ns = 0; ns < 4; ns++)
        #pragma unroll
        for (int r = 0; r < 4; r++) {
            const int m = w * 16 + qb * 4 + r;
            if (m < DX)
                xdbl[((size_t)zi * DX + m) * LL + n0 + ns * 16 + nf] = acc[ns][r];
        }
}

// W_out: M=128, K=256, X = bf16 y, writes d_out fp32 at (zi*CC + m)*LL + n
__global__ __launch_bounds__(256) void gemm_out_mfma(
    const unsigned short* __restrict__ wb, const unsigned short* __restrict__ yb,
    float* __restrict__ outg)
{
    const int zi = blockIdx.z;
    const unsigned short* W = wb + 131072 + (zi >= BB ? 32768 : 0);
    const int mbase = blockIdx.y * 64;
    const unsigned short* Xb = yb + (size_t)zi * DI * LL;
    const int n0 = blockIdx.x * 64;
    const int t = threadIdx.x;
    const int w = t >> 6, ln = t & 63;
    const int nf = ln & 15, qb = ln >> 4;
    bf16x8 afrag[8];
    const int mrow = mbase + w * 16 + nf;
    #pragma unroll
    for (int c = 0; c < 8; c++)
        afrag[c] = *(const bf16x8*)(W + (size_t)mrow * DI + c * 32 + qb * 8);
    __shared__ unsigned short Bs[64][40];
    unsigned* Bw = (unsigned*)Bs;
    f32x4 acc[4] = {};
    const int kp = t >> 4, n4 = (t & 15) * 4;
    #pragma unroll
    for (int kc = 0; kc < 8; kc++) {
        const ushort4 a0 = *(const ushort4*)(Xb + (size_t)(kc * 32 + 2 * kp) * LL + n0 + n4);
        const ushort4 a1 = *(const ushort4*)(Xb + (size_t)(kc * 32 + 2 * kp + 1) * LL + n0 + n4);
        if (kc) __syncthreads();
        Bw[(n4 + 0) * 20 + kp] = (unsigned)a0.x | ((unsigned)a1.x << 16);
        Bw[(n4 + 1) * 20 + kp] = (unsigned)a0.y | ((unsigned)a1.y << 16);
        Bw[(n4 + 2) * 20 + kp] = (unsigned)a0.z | ((unsigned)a1.z << 16);
        Bw[(n4 + 3) * 20 + kp] = (unsigned)a0.w | ((unsigned)a1.w << 16);
        __syncthreads();
        #pragma unroll
        for (int ns = 0; ns < 4; ns++) {
            const bf16x8 bf = *(const bf16x8*)(&Bs[ns * 16 + nf][qb * 8]);
            acc[ns] = __builtin_amdgcn_mfma_f32_16x16x32_bf16(afrag[kc], bf, acc[ns], 0, 0, 0);
        }
    }
    #pragma unroll
    for (int ns = 0; ns < 4; ns++)
        #pragma unroll
        for (int r = 0; r < 4; r++) {
            const int m = mbase + w * 16 + qb * 4 + r;
            outg[((size_t)zi * CC + m) * LL + n0 + ns * 16 + nf] = acc[ns][r];
        }
}

// ================= Fully fused selective scan =================
// One block per (zi,d) row.  delta computed from xdbl dt-rows in staging;
// conv+SiLU fused; chunk-summary prefix (old part2) runs on 16 threads over
// LDS (the carry chain is row-local!); gate emits bf16 y.
__global__ __launch_bounds__(256) void scan_fused(
    const float* __restrict__ xpre, const float* __restrict__ xdbl,
    const float* __restrict__ A_log,
    const float* __restrict__ Wdt0, const float* __restrict__ Wdt1,
    const float* __restrict__ bdt0, const float* __restrict__ bdt1,
    const float* __restrict__ cw0, const float* __restrict__ cb0,
    const float* __restrict__ cw1, const float* __restrict__ cb1,
    const float* __restrict__ D0, const float* __restrict__ D1,
    const float* __restrict__ zbuf, unsigned short* __restrict__ yb)
{
    const int blk = blockIdx.x;          // zi*DI + d
    const int zi = blk >> 8;
    const int d  = blk & (DI - 1);
    const int t = threadIdx.x;
    __shared__ float s0[LL], s1[LL];
    __shared__ float Ssh[DS * 257];      // stride 257: conflict-free both phases
    __shared__ float sdl_sh[NCH];
    const float* x_g = xpre + (size_t)blk * LL;
    const float* xdb = xdbl + (size_t)zi * DX * LL;
    const float* Wdt = (zi >= BB) ? Wdt1 : Wdt0;
    const float* bdt = (zi >= BB) ? bdt1 : bdt0;
    float wdt[DR];
    #pragma unroll
    for (int r = 0; r < DR; r++) wdt[r] = Wdt[d * DR + r];   // d uniform -> scalar
    const float dbias = bdt[d];
    // ---- stage: delta (from dt rows) -> s0, raw x -> s1 (chunk-transposed) ----
    #pragma unroll
    for (int j = 0; j < 4; j++) {
        const int idx = (j * 256 + t) * 4;
        const float4 xv = *(const float4*)(x_g + idx);
        float4 a = {dbias, dbias, dbias, dbias};
        #pragma unroll
        for (int r = 0; r < DR; r++) {
            const float4 v = *(const float4*)(xdb + (size_t)r * LL + idx);
            a.x = fmaf(wdt[r], v.x, a.x); a.y = fmaf(wdt[r], v.y, a.y);
            a.z = fmaf(wdt[r], v.z, a.z); a.w = fmaf(wdt[r], v.w, a.w);
        }
        const int c = idx >> 4, ib = idx & 15;
        s0[SIDX(ib + 0, c)] = softplusf(a.x); s0[SIDX(ib + 1, c)] = softplusf(a.y);
        s0[SIDX(ib + 2, c)] = softplusf(a.z); s0[SIDX(ib + 3, c)] = softplusf(a.w);
        s1[SIDX(ib + 0, c)] = xv.x; s1[SIDX(ib + 1, c)] = xv.y;
        s1[SIDX(ib + 2, c)] = xv.z; s1[SIDX(ib + 3, c)] = xv.w;
    }
    __syncthreads();
    // ---- conv+SiLU + extract to registers ----
    const float* cw = (zi >= BB) ? cw1 : cw0;
    const float* cb = (zi >= BB) ? cb1 : cb0;
    const float w0 = cw[d * 4 + 0], w1 = cw[d * 4 + 1];
    const float w2 = cw[d * 4 + 2], w3 = cw[d * 4 + 3];
    const float cbias = cb[d];
    float xw[CH + 3];
    const int tm1 = (t > 0) ? t - 1 : 0;
    #pragma unroll
    for (int j = 0; j < 3; j++) {
        const float v = s1[SIDX(13 + j, tm1)];
        xw[j] = (t > 0) ? v : 0.f;
    }
    #pragma unroll
    for (int i = 0; i < CH; i++) xw[i + 3] = s1[SIDX(i, t)];
    float rdl[CH], rdlx[CH], rx[CH];
    float sdl = 0.f;
    #pragma unroll
    for (int i = 0; i < CH; i++) {
        rdl[i] = s0[SIDX(i, t)];
        sdl += rdl[i];
        rx[i] = siluf(w0 * xw[i] + w1 * xw[i + 1] + w2 * xw[i + 2] + w3 * xw[i + 3] + cbias);
        rdlx[i] = rdl[i] * rx[i];
    }
    sdl_sh[t] = sdl;
    __syncthreads();               // s0/s1 free; sdl_sh visible
    // ---- phase1: local scans, B rows double-buffered in s0/s1 ----
    const float* Bbase = xdb + (size_t)DR * LL;
    const float* Cbase = Bbase + (size_t)DS * LL;
    {
        #pragma unroll
        for (int j = 0; j < 4; j++) {
            const int idx = (j * 256 + t) * 4;
            const float4 v = *(const float4*)(Bbase + idx);
            const int c = idx >> 4, ib = idx & 15;
            s0[SIDX(ib + 0, c)] = v.x; s0[SIDX(ib + 1, c)] = v.y;
            s0[SIDX(ib + 2, c)] = v.z; s0[SIDX(ib + 3, c)] = v.w;
        }
    }
    __syncthreads();
    for (int n = 0; n < DS; n++) {
        if (n < DS - 1) {
            const float* Bn = Bbase + (size_t)(n + 1) * LL;
            float* dst = ((n + 1) & 1) ? s1 : s0;
            #pragma unroll
            for (int j = 0; j < 4; j++) {
                const int idx = (j * 256 + t) * 4;
                const float4 v = *(const float4*)(Bn + idx);
                const int c = idx >> 4, ib = idx & 15;
                dst[SIDX(ib + 0, c)] = v.x; dst[SIDX(ib + 1, c)] = v.y;
                dst[SIDX(ib + 2, c)] = v.z; dst[SIDX(ib + 3, c)] = v.w;
            }
        }
        const float An = -__expf(A_log[d * DS + n]);
        const float* sb = (n & 1) ? s1 : s0;
        float hn = 0.f;
        #pragma unroll
        for (int i = 0; i < CH; i++) {
            hn = fmaf(__expf(rdl[i] * An), hn, rdlx[i] * sb[SIDX(i, t)]);
        }
        Ssh[n * 257 + t] = hn;
        __syncthreads();
    }
    // ---- phase2: row-local prefix over chunk summaries (16 threads) ----
    if (t < DS) {
        const float An = -__expf(A_log[d * DS + t]);
        float h = 0.f;
        for (int c = 0; c < NCH; c++) {
            const float p = __expf(An * sdl_sh[c]);
            const float tmp = Ssh[t * 257 + c];
            Ssh[t * 257 + c] = h;          // h_in for chunk c
            h = fmaf(p, h, tmp);
        }
    }
    __syncthreads();
    // ---- phase3: re-scan from h_in, y = sum_n h*C ----
    float y[CH];
    #pragma unroll
    for (int i = 0; i < CH; i++) y[i] = 0.f;
    for (int n = 0; n < DS; n++) {
        #pragma unroll
        for (int j = 0; j < 4; j++) {
            const int idx = (j * 256 + t) * 4;
            const float4 bv = *(const float4*)(Bbase + (size_t)n * LL + idx);
            const float4 cv = *(const float4*)(Cbase + (size_t)n * LL + idx);
            const int c = idx >> 4, ib = idx & 15;
            s0[SIDX(ib + 0, c)] = bv.x; s0[SIDX(ib + 1, c)] = bv.y;
            s0[SIDX(ib + 2, c)] = bv.z; s0[SIDX(ib + 3, c)] = bv.w;
            s1[SIDX(ib + 0, c)] = cv.x; s1[SIDX(ib + 1, c)] = cv.y;
            s1[SIDX(ib + 2, c)] = cv.z; s1[SIDX(ib + 3, c)] = cv.w;
        }
        __syncthreads();
        const float An = -__expf(A_log[d * DS + n]);
        float hn = Ssh[n * 257 + t];
        #pragma unroll
        for (int i = 0; i < CH; i++) {
            hn = fmaf(__expf(rdl[i] * An), hn, rdlx[i] * s0[SIDX(i, t)]);
            y[i] = fmaf(hn, s1[SIDX(i, t)], y[i]);
        }
        __syncthreads();
    }
    // ---- gate: y_gated = (y + D*x) * silu(z), emitted as bf16 ----
    #pragma unroll
    for (int i = 0; i < CH; i++) {
        s0[SIDX(i, t)] = y[i];
        s1[SIDX(i, t)] = rx[i];
    }
    const float Dd = ((zi >= BB) ? D1 : D0)[d];
    const float* z_g = zbuf + (size_t)blk * LL;
    unsigned short* y_g = yb + (size_t)blk * LL;
    __syncthreads();
    #pragma unroll
    for (int j = 0; j < 4; j++) {
        const int idx = (j * 256 + t) * 4;
        const int c = idx >> 4, ib = idx & 15;
        const float4 zv = *(const float4*)(z_g + idx);
        ushort4 r;
        r.x = f2bf((s0[SIDX(ib + 0, c)] + Dd * s1[SIDX(ib + 0, c)]) * siluf(zv.x));
        r.y = f2bf((s0[SIDX(ib + 1, c)] + Dd * s1[SIDX(ib + 1, c)]) * siluf(zv.y));
        r.z = f2bf((s0[SIDX(ib + 2, c)] + Dd * s1[SIDX(ib + 2, c)]) * siluf(zv.z));
        r.w = f2bf((s0[SIDX(ib + 3, c)] + Dd * s1[SIDX(ib + 3, c)]) * siluf(zv.w));
        *(ushort4*)(y_g + idx) = r;
    }
}

extern "C" void kernel_launch(void* const* d_in, const int* in_sizes, int n_in,
                              void* d_out, int out_size, void* d_ws, size_t ws_size,
                              hipStream_t stream)
{
    (void)in_sizes; (void)n_in; (void)out_size; (void)ws_size;
    auto fp = [&](int i) { return (const float*)d_in[i]; };
    const float *pan = fp(0), *ms = fp(1);
    const float *nwp = fp(2), *nbp = fp(3), *nwm = fp(4), *nbm = fp(5);
    const float *Winp = fp(6), *Winm = fp(7), *Wzp = fp(8), *Wzm = fp(9);
    const float *cwp = fp(10), *cbp = fp(11), *cwm = fp(12), *cbm = fp(13);
    const float *Wxp = fp(14), *Wxm = fp(15);
    const float *Wdtp = fp(16), *Wdtm = fp(17), *bdtp = fp(18), *bdtm = fp(19);
    const float *Alog = fp(20), *Dp = fp(21), *Dm = fp(22);
    const float *Woutp = fp(23), *Woutm = fp(24);

    float* ws = (float*)d_ws;
    unsigned short* x3b = (unsigned short*)ws;            // NZ*CC*LL bf16
    float* xpre = ws + (size_t)NZ * CC * LL / 2;          // NZ*DI*LL f32
    float* zbuf = xpre + (size_t)NZ * DI * LL;            // NZ*DI*LL f32 (z)
    float* xdbl = zbuf + (size_t)NZ * DI * LL;            // NZ*DX*LL f32
    unsigned short* yb = (unsigned short*)(xdbl + (size_t)NZ * DX * LL); // NZ*DI*LL bf16
    unsigned short* wb = yb + (size_t)NZ * DI * LL;       // 217088 bf16
    float* out = (float*)d_out;

    convert_w_kernel<<<dim3(848), 256, 0, stream>>>(Winp, Winm, Wzp, Wzm, Woutp, Woutm, Wxp, Wxm, wb);
    layernorm_kernel<<<dim3(LL / 64, NZ), 256, 0, stream>>>(pan, ms, nwp, nbp, nwm, nbm, x3b);
    gemm_inz_mfma<<<dim3(LL / 64, 8, NZ), 256, 0, stream>>>(wb, x3b, xpre, zbuf);
    gemm_x_mfma<<<dim3(LL / 64, 1, NZ), 256, 0, stream>>>(wb, xpre, cwp, cbp, cwm, cbm, xdbl);
    scan_fused<<<dim3(NZ * DI), 256, 0, stream>>>(xpre, xdbl, Alog, Wdtp, Wdtm, bdtp, bdtm,
                                                  cwp, cbp, cwm, cbm, Dp, Dm, zbuf, yb);
    gemm_out_mfma<<<dim3(LL / 64, 2, NZ), 256, 0, stream>>>(wb, yb, out);
}

// Round 9
// 215.050 us; speedup vs baseline: 8.7176x; 1.0702x over previous
//
#include <hip/hip_runtime.h>
#include <hip/hip_bf16.h>

// Problem constants
constexpr int BB = 2;        // batch
constexpr int CC = 128;      // channels
constexpr int LL = 4096;     // H*W sequence length
constexpr int DI = 256;      // d_inner
constexpr int DS = 16;       // d_state
constexpr int DR = 8;        // dt_rank
constexpr int DX = 40;       // dt_rank + 2*d_state
constexpr int NZ = 2 * BB;   // branches * batch
constexpr int CH = 16;       // scan chunk length
constexpr int NCH = LL / CH; // 256 chunks == threads per scan WG

typedef short bf16x8 __attribute__((ext_vector_type(8)));
typedef float f32x4 __attribute__((ext_vector_type(4)));

__device__ __forceinline__ unsigned short f2bf(float x) {
    __hip_bfloat16 h = __float2bfloat16(x);
    return *(unsigned short*)&h;
}
__device__ __forceinline__ float siluf(float x) { return x / (1.f + __expf(-x)); }
__device__ __forceinline__ float softplusf(float x) {
    return (x > 20.f) ? x : log1pf(__expf(x));
}

// ---------------- Weight fp32 -> bf16 conversion (once per call) -------------
// Offsets: Winp 0, Winm 32768, Wzp 65536, Wzm 98304, Woutp 131072,
//          Woutm 163840, Wxp 196608, Wxm 206848; total 217088 (= 848*256).
__global__ __launch_bounds__(256) void convert_w_kernel(
    const float* __restrict__ Winp, const float* __restrict__ Winm,
    const float* __restrict__ Wzp, const float* __restrict__ Wzm,
    const float* __restrict__ Woutp, const float* __restrict__ Woutm,
    const float* __restrict__ Wxp, const float* __restrict__ Wxm,
    unsigned short* __restrict__ dst)
{
    const int i = blockIdx.x * 256 + threadIdx.x;
    const float* src; int off;
    if (i < 32768)       { src = Winp;  off = i; }
    else if (i < 65536)  { src = Winm;  off = i - 32768; }
    else if (i < 98304)  { src = Wzp;   off = i - 65536; }
    else if (i < 131072) { src = Wzm;   off = i - 98304; }
    else if (i < 163840) { src = Woutp; off = i - 131072; }
    else if (i < 196608) { src = Woutm; off = i - 163840; }
    else if (i < 206848) { src = Wxp;   off = i - 196608; }
    else                 { src = Wxm;   off = i - 206848; }
    dst[i] = f2bf(src[off]);
}

// ---------------- LayerNorm over C -> bf16 x3, (zi, C, L) layout -------------
__global__ __launch_bounds__(256) void layernorm_kernel(
    const float* __restrict__ pan, const float* __restrict__ ms,
    const float* __restrict__ wpan, const float* __restrict__ bpan,
    const float* __restrict__ wms, const float* __restrict__ bms,
    unsigned short* __restrict__ x3b)
{
    const int zi = blockIdx.y;
    const int br = zi >> 1, b = zi & 1;
    const float* inp = br ? ms : pan;
    const float* wp = br ? wms : wpan;
    const float* bp = br ? bms : bpan;
    const int l0 = blockIdx.x * 64;
    const int t = threadIdx.x;
    const int lo = t & 63, c4 = t >> 6;
    const float* base = inp + (size_t)b * CC * LL + l0 + lo;
    float vals[32];
    float s = 0.f, s2 = 0.f;
    #pragma unroll
    for (int i = 0; i < 32; i++) {
        const int c = c4 * 32 + i;
        const float v = base[(size_t)c * LL];
        vals[i] = v; s += v; s2 += v * v;
    }
    __shared__ float red[2][4][64];
    red[0][c4][lo] = s; red[1][c4][lo] = s2;
    __syncthreads();
    const float S  = red[0][0][lo] + red[0][1][lo] + red[0][2][lo] + red[0][3][lo];
    const float S2 = red[1][0][lo] + red[1][1][lo] + red[1][2][lo] + red[1][3][lo];
    const float mu = S * (1.f / CC);
    const float var = S2 * (1.f / CC) - mu * mu;
    const float rstd = rsqrtf(var + 1e-5f);
    unsigned short* out = x3b + (size_t)zi * CC * LL + l0 + lo;
    #pragma unroll
    for (int i = 0; i < 32; i++) {
        const int c = c4 * 32 + i;
        out[(size_t)c * LL] = f2bf((vals[i] - mu) * rstd * wp[c] + bp[c]);
    }
}

// ================= MFMA bf16 GEMMs =================
// Tile 64M x 64N, 256 thr / 4 waves, K-chunks of 32 staged in LDS [64n][40k].
// A layout: m=lane&15, k=(lane>>4)*8+j.  C/D: col(n)=lane&15, row(m)=(lane>>4)*4+reg.

// Fused W_in + W_z: my 0..3 -> W_in -> xpre; my 4..7 -> W_z -> zy. X = bf16 x3.
__global__ __launch_bounds__(256) void gemm_inz_mfma(
    const unsigned short* __restrict__ wb, const unsigned short* __restrict__ x3b,
    float* __restrict__ xpre, float* __restrict__ zy)
{
    const int zi = blockIdx.z;
    const int my = blockIdx.y;
    const unsigned short* W = wb + (my >= 4 ? 65536 : 0) + (zi >= BB ? 32768 : 0);
    float* outp = (my >= 4) ? zy : xpre;
    const int mbase = (my & 3) * 64;
    const unsigned short* Xb = x3b + (size_t)zi * CC * LL;
    const int n0 = blockIdx.x * 64;
    const int t = threadIdx.x;
    const int w = t >> 6, ln = t & 63;
    const int nf = ln & 15, qb = ln >> 4;
    bf16x8 afrag[4];
    const int mrow = mbase + w * 16 + nf;
    #pragma unroll
    for (int c = 0; c < 4; c++)
        afrag[c] = *(const bf16x8*)(W + (size_t)mrow * CC + c * 32 + qb * 8);
    __shared__ unsigned short Bs[64][40];
    unsigned* Bw = (unsigned*)Bs;
    f32x4 acc[4] = {};
    const int kp = t >> 4, n4 = (t & 15) * 4;
    #pragma unroll
    for (int kc = 0; kc < 4; kc++) {
        const ushort4 a0 = *(const ushort4*)(Xb + (size_t)(kc * 32 + 2 * kp) * LL + n0 + n4);
        const ushort4 a1 = *(const ushort4*)(Xb + (size_t)(kc * 32 + 2 * kp + 1) * LL + n0 + n4);
        if (kc) __syncthreads();
        Bw[(n4 + 0) * 20 + kp] = (unsigned)a0.x | ((unsigned)a1.x << 16);
        Bw[(n4 + 1) * 20 + kp] = (unsigned)a0.y | ((unsigned)a1.y << 16);
        Bw[(n4 + 2) * 20 + kp] = (unsigned)a0.z | ((unsigned)a1.z << 16);
        Bw[(n4 + 3) * 20 + kp] = (unsigned)a0.w | ((unsigned)a1.w << 16);
        __syncthreads();
        #pragma unroll
        for (int ns = 0; ns < 4; ns++) {
            const bf16x8 bf = *(const bf16x8*)(&Bs[ns * 16 + nf][qb * 8]);
            acc[ns] = __builtin_amdgcn_mfma_f32_16x16x32_bf16(afrag[kc], bf, acc[ns], 0, 0, 0);
        }
    }
    #pragma unroll
    for (int ns = 0; ns < 4; ns++)
        #pragma unroll
        for (int r = 0; r < 4; r++) {
            const int m = mbase + w * 16 + qb * 4 + r;
            outp[((size_t)zi * DI + m) * LL + n0 + ns * 16 + nf] = acc[ns][r];
        }
}

// W_x GEMM with fused causal-conv+SiLU staging: xdbl[zi,m,n] =
//   sum_e Wx[m,e] * silu(conv(xpre[zi,e,:]))[n].  M=40 in a 64-row tile.
__global__ __launch_bounds__(256) void gemm_x_mfma(
    const unsigned short* __restrict__ wb, const float* __restrict__ xpre,
    const float* __restrict__ cw0, const float* __restrict__ cb0,
    const float* __restrict__ cw1, const float* __restrict__ cb1,
    float* __restrict__ xdbl)
{
    const int zi = blockIdx.z;
    const unsigned short* W = wb + 196608 + (zi >= BB ? 10240 : 0);
    const float* cw = (zi >= BB) ? cw1 : cw0;
    const float* cb = (zi >= BB) ? cb1 : cb0;
    const float* Xb = xpre + (size_t)zi * DI * LL;
    const int n0 = blockIdx.x * 64;
    const int t = threadIdx.x;
    const int w = t >> 6, ln = t & 63;
    const int nf = ln & 15, qb = ln >> 4;
    bf16x8 zfrag;
    #pragma unroll
    for (int j = 0; j < 8; j++) zfrag[j] = 0;
    bf16x8 afrag[8];
    const int mrow = w * 16 + nf;
    #pragma unroll
    for (int c = 0; c < 8; c++)
        afrag[c] = (mrow < DX) ? *(const bf16x8*)(W + (size_t)mrow * DI + c * 32 + qb * 8) : zfrag;
    __shared__ unsigned short Bs[64][40];
    unsigned* Bw = (unsigned*)Bs;
    f32x4 acc[4] = {};
    const int kp = t >> 4, n4 = (t & 15) * 4;
    #pragma unroll
    for (int kc = 0; kc < 8; kc++) {
        float vals[2][4];
        #pragma unroll
        for (int rr = 0; rr < 2; rr++) {
            const int e = kc * 32 + 2 * kp + rr;
            const float* xp = Xb + (size_t)e * LL + n0 + n4;
            const float4 cur = *(const float4*)xp;
            float xm1, xm2, xm3;
            if (n0 + n4 == 0) { xm1 = 0.f; xm2 = 0.f; xm3 = 0.f; }
            else { xm1 = xp[-1]; xm2 = xp[-2]; xm3 = xp[-3]; }
            const float w0 = cw[e * 4 + 0], w1 = cw[e * 4 + 1];
            const float w2 = cw[e * 4 + 2], w3 = cw[e * 4 + 3];
            const float bias = cb[e];
            vals[rr][0] = siluf(w0 * xm3 + w1 * xm2 + w2 * xm1 + w3 * cur.x + bias);
            vals[rr][1] = siluf(w0 * xm2 + w1 * xm1 + w2 * cur.x + w3 * cur.y + bias);
            vals[rr][2] = siluf(w0 * xm1 + w1 * cur.x + w2 * cur.y + w3 * cur.z + bias);
            vals[rr][3] = siluf(w0 * cur.x + w1 * cur.y + w2 * cur.z + w3 * cur.w + bias);
        }
        if (kc) __syncthreads();
        #pragma unroll
        for (int j = 0; j < 4; j++)
            Bw[(n4 + j) * 20 + kp] = (unsigned)f2bf(vals[0][j]) | ((unsigned)f2bf(vals[1][j]) << 16);
        __syncthreads();
        #pragma unroll
        for (int ns = 0; ns < 4; ns++) {
            const bf16x8 bf = *(const bf16x8*)(&Bs[ns * 16 + nf][qb * 8]);
            acc[ns] = __builtin_amdgcn_mfma_f32_16x16x32_bf16(afrag[kc], bf, acc[ns], 0, 0, 0);
        }
    }
    #pragma unroll
    for (int ns = 0; ns < 4; ns++)
        #pragma unroll
        for (int r = 0; r < 4; r++) {
            const int m = w * 16 + qb * 4 + r;
            if (m < DX)
                xdbl[((size_t)zi * DX + m) * LL + n0 + ns * 16 + nf] = acc[ns][r];
        }
}

// W_out: M=128, K=256, X = bf16 y, writes d_out fp32 at (zi*CC + m)*LL + n
__global__ __launch_bounds__(256) void gemm_out_mfma(
    const unsigned short* __restrict__ wb, const unsigned short* __restrict__ yb,
    float* __restrict__ outg)
{
    const int zi = blockIdx.z;
    const unsigned short* W = wb + 131072 + (zi >= BB ? 32768 : 0);
    const int mbase = blockIdx.y * 64;
    const unsigned short* Xb = yb + (size_t)zi * DI * LL;
    const int n0 = blockIdx.x * 64;
    const int t = threadIdx.x;
    const int w = t >> 6, ln = t & 63;
    const int nf = ln & 15, qb = ln >> 4;
    bf16x8 afrag[8];
    const int mrow = mbase + w * 16 + nf;
    #pragma unroll
    for (int c = 0; c < 8; c++)
        afrag[c] = *(const bf16x8*)(W + (size_t)mrow * DI + c * 32 + qb * 8);
    __shared__ unsigned short Bs[64][40];
    unsigned* Bw = (unsigned*)Bs;
    f32x4 acc[4] = {};
    const int kp = t >> 4, n4 = (t & 15) * 4;
    #pragma unroll
    for (int kc = 0; kc < 8; kc++) {
        const ushort4 a0 = *(const ushort4*)(Xb + (size_t)(kc * 32 + 2 * kp) * LL + n0 + n4);
        const ushort4 a1 = *(const ushort4*)(Xb + (size_t)(kc * 32 + 2 * kp + 1) * LL + n0 + n4);
        if (kc) __syncthreads();
        Bw[(n4 + 0) * 20 + kp] = (unsigned)a0.x | ((unsigned)a1.x << 16);
        Bw[(n4 + 1) * 20 + kp] = (unsigned)a0.y | ((unsigned)a1.y << 16);
        Bw[(n4 + 2) * 20 + kp] = (unsigned)a0.z | ((unsigned)a1.z << 16);
        Bw[(n4 + 3) * 20 + kp] = (unsigned)a0.w | ((unsigned)a1.w << 16);
        __syncthreads();
        #pragma unroll
        for (int ns = 0; ns < 4; ns++) {
            const bf16x8 bf = *(const bf16x8*)(&Bs[ns * 16 + nf][qb * 8]);
            acc[ns] = __builtin_amdgcn_mfma_f32_16x16x32_bf16(afrag[kc], bf, acc[ns], 0, 0, 0);
        }
    }
    #pragma unroll
    for (int ns = 0; ns < 4; ns++)
        #pragma unroll
        for (int r = 0; r < 4; r++) {
            const int m = mbase + w * 16 + qb * 4 + r;
            outg[((size_t)zi * CC + m) * LL + n0 + ns * 16 + nf] = acc[ns][r];
        }
}

// ================= Fully fused selective scan (direct L2 loads) =============
// One block per (zi,d) row; thread t owns chunk [t*16, t*16+16).
// All row data (dt-rows, x, B, C, z) loaded straight from global (L2-resident
// xdbl = 655 KB/zi) in 4x float4 per 64-B chunk span — no LDS transpose.
// LDS holds only the chunk summaries (Ssh) and per-chunk delta sums.
__global__ __launch_bounds__(256) void scan_fused(
    const float* __restrict__ xpre, const float* __restrict__ xdbl,
    const float* __restrict__ A_log,
    const float* __restrict__ Wdt0, const float* __restrict__ Wdt1,
    const float* __restrict__ bdt0, const float* __restrict__ bdt1,
    const float* __restrict__ cw0, const float* __restrict__ cb0,
    const float* __restrict__ cw1, const float* __restrict__ cb1,
    const float* __restrict__ D0, const float* __restrict__ D1,
    const float* __restrict__ zbuf, unsigned short* __restrict__ yb)
{
    const int blk = blockIdx.x;          // zi*DI + d
    const int zi = blk >> 8;
    const int d  = blk & (DI - 1);
    const int t = threadIdx.x;
    const int l0 = t * CH;
    __shared__ float Ssh[DS * 257];      // stride 257: conflict-free both phases
    __shared__ float sdl_sh[NCH];
    const float* x_g = xpre + (size_t)blk * LL;
    const float* xdb = xdbl + (size_t)zi * DX * LL;
    const float* Wdt = (zi >= BB) ? Wdt1 : Wdt0;
    const float* bdt = (zi >= BB) ? bdt1 : bdt0;
    const float dbias = bdt[d];
    // ---- delta: a[i] = dbias + sum_r wdt[r]*dtrow_r[l0+i], direct loads ----
    float a[CH];
    #pragma unroll
    for (int i = 0; i < CH; i++) a[i] = dbias;
    #pragma unroll
    for (int r = 0; r < DR; r++) {
        const float wr = Wdt[d * DR + r];
        const float* rp = xdb + (size_t)r * LL + l0;
        #pragma unroll
        for (int j = 0; j < 4; j++) {
            const float4 v = *(const float4*)(rp + 4 * j);
            a[4 * j + 0] = fmaf(wr, v.x, a[4 * j + 0]);
            a[4 * j + 1] = fmaf(wr, v.y, a[4 * j + 1]);
            a[4 * j + 2] = fmaf(wr, v.z, a[4 * j + 2]);
            a[4 * j + 3] = fmaf(wr, v.w, a[4 * j + 3]);
        }
    }
    float rdl[CH];
    float sdl = 0.f;
    #pragma unroll
    for (int i = 0; i < CH; i++) { rdl[i] = softplusf(a[i]); sdl += rdl[i]; }
    sdl_sh[t] = sdl;
    // ---- x + conv + SiLU, direct loads (halo float4 at l0-4) ----
    const float* cw = (zi >= BB) ? cw1 : cw0;
    const float* cb = (zi >= BB) ? cb1 : cb0;
    const float w0 = cw[d * 4 + 0], w1 = cw[d * 4 + 1];
    const float w2 = cw[d * 4 + 2], w3 = cw[d * 4 + 3];
    const float cbias = cb[d];
    float xv[CH + 3];
    if (t > 0) {
        const float4 hm = *(const float4*)(x_g + l0 - 4);
        xv[0] = hm.y; xv[1] = hm.z; xv[2] = hm.w;
    } else { xv[0] = 0.f; xv[1] = 0.f; xv[2] = 0.f; }
    #pragma unroll
    for (int j = 0; j < 4; j++) {
        const float4 v = *(const float4*)(x_g + l0 + 4 * j);
        xv[4 * j + 3] = v.x; xv[4 * j + 4] = v.y;
        xv[4 * j + 5] = v.z; xv[4 * j + 6] = v.w;
    }
    float rx[CH], rdlx[CH];
    #pragma unroll
    for (int i = 0; i < CH; i++) {
        rx[i] = siluf(w0 * xv[i] + w1 * xv[i + 1] + w2 * xv[i + 2] + w3 * xv[i + 3] + cbias);
        rdlx[i] = rdl[i] * rx[i];
    }
    // ---- A decay factors (block-uniform row) ----
    float An[DS];
    #pragma unroll
    for (int n = 0; n < DS; n++) An[n] = -__expf(A_log[d * DS + n]);
    // ---- phase1: local scans (h_in = 0), direct B loads ----
    const float* Bbase = xdb + (size_t)DR * LL;
    const float* Cbase = Bbase + (size_t)DS * LL;
    #pragma unroll 4
    for (int n = 0; n < DS; n++) {
        const float* bp = Bbase + (size_t)n * LL + l0;
        float hn = 0.f;
        #pragma unroll
        for (int j = 0; j < 4; j++) {
            const float4 bv = *(const float4*)(bp + 4 * j);
            hn = fmaf(__expf(rdl[4 * j + 0] * An[n]), hn, rdlx[4 * j + 0] * bv.x);
            hn = fmaf(__expf(rdl[4 * j + 1] * An[n]), hn, rdlx[4 * j + 1] * bv.y);
            hn = fmaf(__expf(rdl[4 * j + 2] * An[n]), hn, rdlx[4 * j + 2] * bv.z);
            hn = fmaf(__expf(rdl[4 * j + 3] * An[n]), hn, rdlx[4 * j + 3] * bv.w);
        }
        Ssh[n * 257 + t] = hn;
    }
    __syncthreads();
    // ---- phase2: row-local prefix over chunk summaries (16 threads) ----
    if (t < DS) {
        const float Ann = An[t];
        float h = 0.f;
        for (int c = 0; c < NCH; c++) {
            const float p = __expf(Ann * sdl_sh[c]);
            const float tmp = Ssh[t * 257 + c];
            Ssh[t * 257 + c] = h;          // h_in for chunk c
            h = fmaf(p, h, tmp);
        }
    }
    __syncthreads();
    // ---- phase3: re-scan from h_in, y = sum_n h*C, direct B/C loads ----
    float y[CH];
    #pragma unroll
    for (int i = 0; i < CH; i++) y[i] = 0.f;
    #pragma unroll 4
    for (int n = 0; n < DS; n++) {
        const float* bp = Bbase + (size_t)n * LL + l0;
        const float* cp = Cbase + (size_t)n * LL + l0;
        float hn = Ssh[n * 257 + t];
        #pragma unroll
        for (int j = 0; j < 4; j++) {
            const float4 bv = *(const float4*)(bp + 4 * j);
            const float4 cv = *(const float4*)(cp + 4 * j);
            hn = fmaf(__expf(rdl[4 * j + 0] * An[n]), hn, rdlx[4 * j + 0] * bv.x);
            y[4 * j + 0] = fmaf(hn, cv.x, y[4 * j + 0]);
            hn = fmaf(__expf(rdl[4 * j + 1] * An[n]), hn, rdlx[4 * j + 1] * bv.y);
            y[4 * j + 1] = fmaf(hn, cv.y, y[4 * j + 1]);
            hn = fmaf(__expf(rdl[4 * j + 2] * An[n]), hn, rdlx[4 * j + 2] * bv.z);
            y[4 * j + 2] = fmaf(hn, cv.z, y[4 * j + 2]);
            hn = fmaf(__expf(rdl[4 * j + 3] * An[n]), hn, rdlx[4 * j + 3] * bv.w);
            y[4 * j + 3] = fmaf(hn, cv.w, y[4 * j + 3]);
        }
    }
    // ---- gate: y_gated = (y + D*x) * silu(z), bf16 out, direct z loads ----
    const float Dd = ((zi >= BB) ? D1 : D0)[d];
    const float* z_g = zbuf + (size_t)blk * LL + l0;
    unsigned short* y_g = yb + (size_t)blk * LL + l0;
    #pragma unroll
    for (int j = 0; j < 4; j++) {
        const float4 zv = *(const float4*)(z_g + 4 * j);
        ushort4 r;
        r.x = f2bf((y[4 * j + 0] + Dd * rx[4 * j + 0]) * siluf(zv.x));
        r.y = f2bf((y[4 * j + 1] + Dd * rx[4 * j + 1]) * siluf(zv.y));
        r.z = f2bf((y[4 * j + 2] + Dd * rx[4 * j + 2]) * siluf(zv.z));
        r.w = f2bf((y[4 * j + 3] + Dd * rx[4 * j + 3]) * siluf(zv.w));
        *(ushort4*)(y_g + 4 * j) = r;
    }
}

extern "C" void kernel_launch(void* const* d_in, const int* in_sizes, int n_in,
                              void* d_out, int out_size, void* d_ws, size_t ws_size,
                              hipStream_t stream)
{
    (void)in_sizes; (void)n_in; (void)out_size; (void)ws_size;
    auto fp = [&](int i) { return (const float*)d_in[i]; };
    const float *pan = fp(0), *ms = fp(1);
    const float *nwp = fp(2), *nbp = fp(3), *nwm = fp(4), *nbm = fp(5);
    const float *Winp = fp(6), *Winm = fp(7), *Wzp = fp(8), *Wzm = fp(9);
    const float *cwp = fp(10), *cbp = fp(11), *cwm = fp(12), *cbm = fp(13);
    const float *Wxp = fp(14), *Wxm = fp(15);
    const float *Wdtp = fp(16), *Wdtm = fp(17), *bdtp = fp(18), *bdtm = fp(19);
    const float *Alog = fp(20), *Dp = fp(21), *Dm = fp(22);
    const float *Woutp = fp(23), *Woutm = fp(24);

    float* ws = (float*)d_ws;
    unsigned short* x3b = (unsigned short*)ws;            // NZ*CC*LL bf16
    float* xpre = ws + (size_t)NZ * CC * LL / 2;          // NZ*DI*LL f32
    float* zbuf = xpre + (size_t)NZ * DI * LL;            // NZ*DI*LL f32 (z)
    float* xdbl = zbuf + (size_t)NZ * DI * LL;            // NZ*DX*LL f32
    unsigned short* yb = (unsigned short*)(xdbl + (size_t)NZ * DX * LL); // NZ*DI*LL bf16
    unsigned short* wb = yb + (size_t)NZ * DI * LL;       // 217088 bf16
    float* out = (float*)d_out;

    convert_w_kernel<<<dim3(848), 256, 0, stream>>>(Winp, Winm, Wzp, Wzm, Woutp, Woutm, Wxp, Wxm, wb);
    layernorm_kernel<<<dim3(LL / 64, NZ), 256, 0, stream>>>(pan, ms, nwp, nbp, nwm, nbm, x3b);
    gemm_inz_mfma<<<dim3(LL / 64, 8, NZ), 256, 0, stream>>>(wb, x3b, xpre, zbuf);
    gemm_x_mfma<<<dim3(LL / 64, 1, NZ), 256, 0, stream>>>(wb, xpre, cwp, cbp, cwm, cbm, xdbl);
    scan_fused<<<dim3(NZ * DI), 256, 0, stream>>>(xpre, xdbl, Alog, Wdtp, Wdtm, bdtp, bdtm,
                                                  cwp, cbp, cwm, cbm, Dp, Dm, zbuf, yb);
    gemm_out_mfma<<<dim3(LL / 64, 2, NZ), 256, 0, stream>>>(wb, yb, out);
}